// Round 6
// baseline (467.766 us; speedup 1.0000x reference)
//
#include <hip/hip_runtime.h>
#include <hip/hip_bf16.h>

#define B_ 8
#define L_ 512
#define T_ 512
#define D_ 768
#define H_ 12
#define DH_ 64
#define SD_ 5
#define NSW_ 72   // H*(SD+1)
#define K2_ 1536  // split A:  [hi | lo]
#define K3_ 2304  // split W:  [hi | lo | hi]

typedef __attribute__((ext_vector_type(8))) short bf16x8;
typedef __attribute__((ext_vector_type(4))) float f32x4;
typedef unsigned short ushort_t;

__device__ __forceinline__ unsigned short f2bf(float x) {
    union { __hip_bfloat16 h; unsigned short u; } cv;
    cv.h = __float2bfloat16(x);
    return cv.u;
}
__device__ __forceinline__ float bf2f(unsigned short u) {
    union { unsigned short u; __hip_bfloat16 h; } cv;
    cv.u = u;
    return __bfloat162float(cv.h);
}

__device__ __forceinline__ void gload_lds16(const void* g, void* l) {
    __builtin_amdgcn_global_load_lds((const __attribute__((address_space(1))) void*)g,
                                     (__attribute__((address_space(3))) void*)l,
                                     16, 0, 0);
}

// ---------------------------------------------------------------------------
// Split fp32 activations -> A2 = [hi | lo] bf16, row-major [M][1536].
// ---------------------------------------------------------------------------
__global__ __launch_bounds__(256) void asplit_kernel(
    const float* __restrict__ q, const float* __restrict__ k, const float* __restrict__ v,
    short* __restrict__ q2, short* __restrict__ k2, short* __restrict__ v2)
{
    const int z = blockIdx.z;
    const float* A = (z == 0) ? q : (z == 1) ? k : v;
    short* O = (z == 0) ? q2 : (z == 1) ? k2 : v2;
    const int col = blockIdx.x * 256 + threadIdx.x;
    const int m   = blockIdx.y;
    if (col >= D_) return;
    const float a = A[(size_t)m * D_ + col];
    const unsigned short hi = f2bf(a);
    const unsigned short lo = f2bf(a - bf2f(hi));
    O[(size_t)m * K2_ + col]       = (short)hi;
    O[(size_t)m * K2_ + D_ + col]  = (short)lo;
}

// ---------------------------------------------------------------------------
// Transpose + split weights -> WT3 [Npad x 2304]: row n = [hi | lo | hi].
// ---------------------------------------------------------------------------
__global__ __launch_bounds__(256) void wsplit_kernel(
    const float* __restrict__ Wq, const float* __restrict__ Wk,
    const float* __restrict__ Wv, const float* __restrict__ Wl,
    const float* __restrict__ Wf,
    short* __restrict__ WqT3, short* __restrict__ WkT3, short* __restrict__ WvT3,
    short* __restrict__ WlT3, short* __restrict__ WfT3)
{
    const int z = blockIdx.z;
    const float* W; short* O; int Nw, Npad;
    if (z == 0)      { W = Wq; O = WqT3; Nw = D_;   Npad = 768; }
    else if (z == 1) { W = Wk; O = WkT3; Nw = D_;   Npad = 768; }
    else if (z == 2) { W = Wv; O = WvT3; Nw = D_;   Npad = 768; }
    else if (z == 3) { W = Wl; O = WlT3; Nw = NSW_; Npad = 128; }
    else             { W = Wf; O = WfT3; Nw = D_;   Npad = 768; }

    const int k0 = blockIdx.x * 64;
    const int n0 = blockIdx.y * 64;
    if (n0 >= Npad) return;

    __shared__ float sm[64][65];
    const int c  = threadIdx.x & 63;
    const int r4 = threadIdx.x >> 6;

#pragma unroll
    for (int i = 0; i < 16; i++) {
        const int r = i * 4 + r4;
        float val = 0.f;
        if (n0 + c < Nw) val = W[(size_t)(k0 + r) * Nw + n0 + c];
        sm[r][c] = val;
    }
    __syncthreads();

#pragma unroll
    for (int i = 0; i < 16; i++) {
        const int nl = i * 4 + r4;
        const int n  = n0 + nl;
        if (n >= Npad) continue;
        const float v = (n < Nw) ? sm[c][nl] : 0.f;
        const unsigned short hi = f2bf(v);
        const unsigned short lo = f2bf(v - bf2f(hi));
        const size_t rb = (size_t)n * K3_;
        O[rb + k0 + c]        = (short)hi;
        O[rb + 768 + k0 + c]  = (short)lo;
        O[rb + 1536 + k0 + c] = (short)hi;
    }
}

// ---------------------------------------------------------------------------
// MFMA GEMM (split-bf16, K=2304), BK=64, XOR-swizzled LDS, XCD block swizzle,
// 2-deep double-buffered pipeline with counted vmcnt; kk-split interleave:
// MFMA(kk0) overlaps the kk1 ds_reads (counted lgkmcnt) and MFMA(kk1)
// overlaps the next-tile staging. setprio(1) around MFMA clusters.
// ---------------------------------------------------------------------------
__global__ __launch_bounds__(256) void mfma_gemm(
    const short* __restrict__ q2, const short* __restrict__ k2, const short* __restrict__ v2,
    const short* __restrict__ WqT3, const short* __restrict__ WkT3,
    const short* __restrict__ WvT3, const short* __restrict__ WlT3,
    const short* __restrict__ WfT3,
    const float* __restrict__ bq, const float* __restrict__ bk,
    const float* __restrict__ bv, const float* __restrict__ bl,
    const float* __restrict__ bf,
    const short* __restrict__ outp2,
    ushort_t* __restrict__ qs2a, ushort_t* __restrict__ ks2a, ushort_t* __restrict__ vt2,
    float* __restrict__ swv, float* __restrict__ outf,
    int zoff)
{
    const int nwg   = gridDim.x * gridDim.y * gridDim.z;
    const int flat  = blockIdx.x + gridDim.x * (blockIdx.y + gridDim.y * blockIdx.z);
    const int flat2 = (flat & 7) * (nwg >> 3) + (flat >> 3);
    const int bxg   = flat2 % 6;
    const int rem   = flat2 / 6;
    const int byg   = rem & 31;
    const int bzg   = rem >> 5;

    const int z = zoff + bzg;
    const short* A2; const short* WT3; const float* bias;
    if (z == 0)      { A2 = q2;    WT3 = WqT3; bias = bq; }
    else if (z == 1) { A2 = k2;    WT3 = WkT3; bias = bk; }
    else if (z == 2) { A2 = v2;    WT3 = WvT3; bias = bv; }
    else if (z == 3) { A2 = q2;    WT3 = WlT3; bias = bl; }
    else             { A2 = outp2; WT3 = WfT3; bias = bf; }

    if (z == 3 && bxg != 0) return;

    const int m0 = byg * 128;
    const int n0 = bxg * 128;

    __shared__ __align__(16) short As[2][128 * 64];
    __shared__ __align__(16) short Bs[2][128 * 64];

    const int tid  = threadIdx.x;
    const int lane = tid & 63;
    const int wv_  = tid >> 6;
    const int wm   = (wv_ & 1) << 6;
    const int wn   = (wv_ >> 1) << 6;
    const int l15  = lane & 15;
    const int quad = lane >> 4;

    f32x4 acc[4][4] = {};

    const int NT = K3_ / 64;   // 36 K-steps

    auto stage = [&](int buf, int kb) {
        const int akb = (kb < 768) ? kb : kb - 768;  // A=[hi|lo]; W=[hi|lo|hi]
#pragma unroll
        for (int j = 0; j < 4; j++) {
            const int i = tid + 256 * j;
            const int r = i >> 3, c = i & 7, gc = c ^ (r & 7);
            gload_lds16(A2 + (size_t)(m0 + r) * K2_ + akb + gc * 8, &As[buf][i * 8]);
        }
#pragma unroll
        for (int j = 0; j < 4; j++) {
            const int i = tid + 256 * j;
            const int r = i >> 3, c = i & 7, gc = c ^ (r & 7);
            gload_lds16(WT3 + (size_t)(n0 + r) * K3_ + kb + gc * 8, &Bs[buf][i * 8]);
        }
    };

    stage(0, 0);
    stage(1, 64);

    int cur = 0;
    for (int t = 0; t < NT; ++t) {
        asm volatile("s_waitcnt vmcnt(8)" ::: "memory");
        __builtin_amdgcn_s_barrier();

        bf16x8 af[2][4], bfr[2][4];
        // kk0 read group first (order pinned so lgkmcnt(8) == "kk0 done")
#pragma unroll
        for (int tt = 0; tt < 4; tt++) {
            const int ar = wm + tt * 16 + l15;
            const int br = wn + tt * 16 + l15;
            af[0][tt]  = *(const bf16x8*)&As[cur][ar * 64 + (quad ^ (ar & 7)) * 8];
            bfr[0][tt] = *(const bf16x8*)&Bs[cur][br * 64 + (quad ^ (br & 7)) * 8];
        }
        __builtin_amdgcn_sched_barrier(0);
#pragma unroll
        for (int tt = 0; tt < 4; tt++) {
            const int ar = wm + tt * 16 + l15;
            const int br = wn + tt * 16 + l15;
            af[1][tt]  = *(const bf16x8*)&As[cur][ar * 64 + ((4 + quad) ^ (ar & 7)) * 8];
            bfr[1][tt] = *(const bf16x8*)&Bs[cur][br * 64 + ((4 + quad) ^ (br & 7)) * 8];
        }
        __builtin_amdgcn_sched_barrier(0);

        // kk0 MFMAs overlap the kk1 reads still in flight
        asm volatile("s_waitcnt lgkmcnt(8)" ::: "memory");
        __builtin_amdgcn_sched_barrier(0);
        __builtin_amdgcn_s_setprio(1);
#pragma unroll
        for (int mt = 0; mt < 4; mt++)
#pragma unroll
            for (int nt = 0; nt < 4; nt++)
                acc[mt][nt] = __builtin_amdgcn_mfma_f32_16x16x32_bf16(
                    af[0][mt], bfr[0][nt], acc[mt][nt], 0, 0, 0);
        __builtin_amdgcn_s_setprio(0);

        asm volatile("s_waitcnt lgkmcnt(0)" ::: "memory");
        __builtin_amdgcn_sched_barrier(0);
        __builtin_amdgcn_s_barrier();     // all waves' reads done -> buffer reusable

        const int kb2 = (t + 2 < NT) ? (t + 2) * 64 : 0;
        stage(cur, kb2);
        __builtin_amdgcn_sched_barrier(0);

        __builtin_amdgcn_s_setprio(1);
#pragma unroll
        for (int mt = 0; mt < 4; mt++)
#pragma unroll
            for (int nt = 0; nt < 4; nt++)
                acc[mt][nt] = __builtin_amdgcn_mfma_f32_16x16x32_bf16(
                    af[1][mt], bfr[1][nt], acc[mt][nt], 0, 0, 0);
        __builtin_amdgcn_s_setprio(0);
        cur ^= 1;
    }
    asm volatile("s_waitcnt vmcnt(0)" ::: "memory");

    if (z <= 2) {
        ushort_t* dst = (z == 0) ? qs2a : (z == 1) ? ks2a : vt2;
#pragma unroll
        for (int nt = 0; nt < 4; nt++) {
            const int col = n0 + wn + nt * 16 + l15;
            const int hh = col >> 6, dd = col & 63;
            const float bvv = bias[col];
#pragma unroll
            for (int mt = 0; mt < 4; mt++) {
                const int rowb = m0 + wm + mt * 16 + quad * 4;
                if (z < 2) {
#pragma unroll
                    for (int r = 0; r < 4; r++) {
                        const int gr = rowb + r;
                        const int bb = gr >> 9, ll = gr & 511;
                        const float x = acc[mt][nt][r] + bvv;
                        const ushort_t hi = f2bf(x);
                        const ushort_t lo = f2bf(x - bf2f(hi));
                        const size_t base = (((size_t)hh * B_ + bb) * 512 + ll) * 128 + dd;
                        dst[base]      = hi;
                        dst[base + 64] = lo;
                    }
                } else {
                    const int bb = rowb >> 9, tt = rowb & 511;
                    ushort_t hi4[4], lo4[4];
#pragma unroll
                    for (int r = 0; r < 4; r++) {
                        const float x = acc[mt][nt][r] + bvv;
                        hi4[r] = f2bf(x);
                        lo4[r] = f2bf(x - bf2f(hi4[r]));
                    }
                    const size_t base = (((size_t)hh * B_ + bb) * 128 + dd) * 512 + tt;
                    *(ushort4*)&dst[base]            = *(ushort4*)hi4;
                    *(ushort4*)&dst[base + 64 * 512] = *(ushort4*)lo4;
                }
            }
        }
    } else if (z == 3) {
#pragma unroll
        for (int nt = 0; nt < 4; nt++) {
            const int col = n0 + wn + nt * 16 + l15;
            if (col >= NSW_) continue;
            const float bvv = bias[col];
#pragma unroll
            for (int mt = 0; mt < 4; mt++) {
                const int row = m0 + wm + mt * 16 + quad * 4;
#pragma unroll
                for (int r = 0; r < 4; r++)
                    swv[(size_t)(row + r) * NSW_ + col] = acc[mt][nt][r] + bvv;
            }
        }
    } else {
#pragma unroll
        for (int nt = 0; nt < 4; nt++) {
            const int col = n0 + wn + nt * 16 + l15;
            const float bvv = bias[col];
#pragma unroll
            for (int mt = 0; mt < 4; mt++) {
                const int row = m0 + wm + mt * 16 + quad * 4;
#pragma unroll
                for (int r = 0; r < 4; r++)
                    outf[(size_t)(row + r) * D_ + col] = acc[mt][nt][r] + bvv;
            }
        }
    }
}

// ---------------------------------------------------------------------------
// sig16[h][b][l][t] = mask ? 0 : max(sigmoid(bias_h + w_h · ploc[b,l,t,:]), 1e-6)
// ---------------------------------------------------------------------------
__global__ __launch_bounds__(256) void sig_kernel(
    const float* __restrict__ ploc, const float* __restrict__ swv,
    const int* __restrict__ maskp, _Float16* __restrict__ sig16)
{
    const int b = blockIdx.y;
    const int l = blockIdx.x;
    const int tid = threadIdx.x;

    __shared__ float pls[512 * 5];
    __shared__ float sws[72];
    __shared__ int   msk[512];

    const float* src = ploc + (size_t)(b * 512 + l) * 512 * 5;
    for (int i = tid; i < 640; i += 256)
        *(float4*)&pls[i * 4] = *(const float4*)(src + i * 4);
    if (tid < 72) sws[tid] = swv[(size_t)(b * 512 + l) * NSW_ + tid];
    for (int i = tid; i < 512; i += 256) msk[i] = maskp[b * 512 + i];
    __syncthreads();

    for (int e = tid; e < H_ * 512; e += 256) {
        const int t  = e & 511;
        const int hh = e >> 9;
        float s = sws[hh * 6];
#pragma unroll
        for (int d = 0; d < SD_; d++) s += sws[hh * 6 + 1 + d] * pls[t * 5 + d];
        const float sig = msk[t] ? 0.f : fmaxf(1.f / (1.f + __expf(-s)), 1e-6f);
        sig16[(((size_t)hh * B_ + b) * 512 + l) * 512 + t] = (_Float16)sig;
    }
}

// ---------------------------------------------------------------------------
// MFMA attention v3 — pipelined (Q in regs, K dbuf counted vmcnt, V staged
// under QK), setprio around MFMA clusters, and fused normalization: after
// row sums are known, this block rescales its own (L2-hot) fused slice.
// ---------------------------------------------------------------------------
__global__ __launch_bounds__(256) void attn_kernel(
    const ushort_t* __restrict__ qs2, const ushort_t* __restrict__ ks2,
    const ushort_t* __restrict__ vt2, const _Float16* __restrict__ sig16,
    float* __restrict__ fused, ushort_t* __restrict__ outp2,
    float* __restrict__ sums)
{
    // grid (8,8,12) = 768 blocks; bijective XCD swizzle, x (l-tile) fastest.
    const int flat  = blockIdx.x + 8 * (blockIdx.y + 8 * blockIdx.z);
    const int flat2 = (flat & 7) * 96 + (flat >> 3);
    const int h  = flat2 / 64;
    const int b  = (flat2 >> 3) & 7;
    const int l0 = (flat2 & 7) << 6;

    const int hb = h * B_ + b;
    const int tid  = threadIdx.x;
    const int lane = tid & 63;
    const int wv   = tid >> 6;
    const int l15  = lane & 15;
    const int quad = lane >> 4;

    __shared__ __align__(16) ushort_t ks[2][64 * 128];
    __shared__ __align__(16) ushort_t vts[128 * 64];
    __shared__ __align__(16) ushort_t ps[64 * 152];   // [l][hi 0-63 | lo 64-127 | pad]
    __shared__ float ssb[4 * 64];
    __shared__ float ssum[64];

    // Q fragments straight to registers
    bf16x8 qreg[4][4];
    {
        const ushort_t* qb = qs2 + ((size_t)hb * 512 + l0) * 128;
#pragma unroll
        for (int mt = 0; mt < 4; mt++) {
            const ushort_t* qr = qb + (size_t)(mt * 16 + l15) * 128 + quad * 8;
            qreg[mt][0] = *(const bf16x8*)(qr);
            qreg[mt][1] = *(const bf16x8*)(qr + 32);
            qreg[mt][2] = *(const bf16x8*)(qr + 64);
            qreg[mt][3] = *(const bf16x8*)(qr + 96);
        }
    }

    float pacc = 0.f;
    f32x4 accpv[4] = {};

    auto stageK = [&](int buf, int t0s) {
        const size_t kbase = ((size_t)hb * 512 + t0s) * 128;
#pragma unroll
        for (int j = 0; j < 4; j++) {
            const int i = tid + 256 * j;
            const int r = i >> 4, c = i & 15, gc = c ^ (r & 7);
            gload_lds16(ks2 + kbase + r * 128 + gc * 8, &ks[buf][i * 8]);
        }
    };
    auto stageV = [&](int t0s) {
        const size_t vbase = (size_t)hb * 128 * 512;
#pragma unroll
        for (int j = 0; j < 4; j++) {
            const int i = tid + 256 * j;
            const int r = i >> 3, c = i & 7, gc = c ^ (r & 7);
            gload_lds16(vt2 + vbase + (size_t)r * 512 + t0s + gc * 8, &vts[i * 8]);
        }
    };

    stageK(0, 0);

#pragma unroll 1
    for (int it = 0; it < 8; ++it) {
        const int t0  = it << 6;
        const int cur = it & 1;
        if (it == 0) asm volatile("s_waitcnt vmcnt(0)" ::: "memory");
        else         asm volatile("s_waitcnt vmcnt(4)" ::: "memory");
        __builtin_amdgcn_sched_barrier(0);
        __builtin_amdgcn_s_barrier();   // K(it) visible; prev-iter LDS reads done

        float sigv[4][4];
        {
            const _Float16* sgp = sig16 + (((size_t)hb * 512 + l0) * 512) + t0 + wv * 16 + l15;
#pragma unroll
            for (int mt = 0; mt < 4; mt++)
#pragma unroll
                for (int r2 = 0; r2 < 4; r2++)
                    sigv[mt][r2] = (float)sgp[(size_t)(mt * 16 + quad * 4 + r2) * 512];
        }
        __builtin_amdgcn_sched_barrier(0);
        stageV(t0);                                   // V(it): drained at mid-barrier
        stageK(cur ^ 1, (it < 7) ? t0 + 64 : 0);      // K(it+1): drained next iter-top
        __builtin_amdgcn_sched_barrier(0);

        // ---- QK ----
        f32x4 acq[4] = {};
        {
            const int trow = wv * 16 + l15;
            const int tsw  = trow & 7;
            const bf16x8 bk0 = *(const bf16x8*)&ks[cur][trow * 128 + ((0  + quad) ^ tsw) * 8];
            const bf16x8 bk1 = *(const bf16x8*)&ks[cur][trow * 128 + ((4  + quad) ^ tsw) * 8];
            const bf16x8 bk2 = *(const bf16x8*)&ks[cur][trow * 128 + ((8  + quad) ^ tsw) * 8];
            const bf16x8 bk3 = *(const bf16x8*)&ks[cur][trow * 128 + ((12 + quad) ^ tsw) * 8];
            __builtin_amdgcn_s_setprio(1);
#pragma unroll
            for (int mt = 0; mt < 4; mt++) {
                f32x4 a = acq[mt];
                a = __builtin_amdgcn_mfma_f32_16x16x32_bf16(qreg[mt][0], bk0, a, 0, 0, 0);
                a = __builtin_amdgcn_mfma_f32_16x16x32_bf16(qreg[mt][1], bk1, a, 0, 0, 0);
                a = __builtin_amdgcn_mfma_f32_16x16x32_bf16(qreg[mt][0], bk2, a, 0, 0, 0);
                a = __builtin_amdgcn_mfma_f32_16x16x32_bf16(qreg[mt][1], bk3, a, 0, 0, 0);
                a = __builtin_amdgcn_mfma_f32_16x16x32_bf16(qreg[mt][2], bk0, a, 0, 0, 0);
                a = __builtin_amdgcn_mfma_f32_16x16x32_bf16(qreg[mt][3], bk1, a, 0, 0, 0);
                acq[mt] = a;
            }
            __builtin_amdgcn_s_setprio(0);
        }

        // ---- p = sig * exp(qk/8), split to LDS ----
        {
            const int tcol = wv * 16 + l15;
#pragma unroll
            for (int mt = 0; mt < 4; mt++)
#pragma unroll
                for (int r2 = 0; r2 < 4; r2++) {
                    const int lrow = mt * 16 + quad * 4 + r2;
                    const float p  = sigv[mt][r2] * __expf(acq[mt][r2] * 0.125f);
                    const ushort_t hi = f2bf(p);
                    const ushort_t lo = f2bf(p - bf2f(hi));
                    ps[lrow * 152 + tcol]      = hi;
                    ps[lrow * 152 + 64 + tcol] = lo;
                }
        }
        asm volatile("s_waitcnt lgkmcnt(0) vmcnt(4)" ::: "memory");
        __builtin_amdgcn_sched_barrier(0);
        __builtin_amdgcn_s_barrier();

        // ---- fused store (b128 ps reads) + row-sum partials ----
        {
            const int row = tid >> 2, c4 = tid & 3;
            const bf16x8 h0 = *(const bf16x8*)&ps[row * 152 + c4 * 16];
            const bf16x8 h1 = *(const bf16x8*)&ps[row * 152 + c4 * 16 + 8];
            const bf16x8 g0 = *(const bf16x8*)&ps[row * 152 + 64 + c4 * 16];
            const bf16x8 g1 = *(const bf16x8*)&ps[row * 152 + 64 + c4 * 16 + 8];
            float vbuf[16];
            float s = 0.f;
#pragma unroll
            for (int jj = 0; jj < 8; jj++) {
                vbuf[jj]     = bf2f((ushort_t)h0[jj]) + bf2f((ushort_t)g0[jj]);
                vbuf[8 + jj] = bf2f((ushort_t)h1[jj]) + bf2f((ushort_t)g1[jj]);
                s += vbuf[jj] + vbuf[8 + jj];
            }
            pacc += s;
            float* dstf = fused + ((size_t)hb * 512 + l0 + row) * 512 + t0 + c4 * 16;
#pragma unroll
            for (int jj = 0; jj < 4; jj++)
                *(float4*)(dstf + jj * 4) = *(float4*)&vbuf[jj * 4];
        }

        // ---- PV ----
        {
            const int vrh = wv * 16 + l15;
            const int vrl = 64 + vrh;
            const int swh = vrh & 7, swl = vrl & 7;
            const bf16x8 bh0 = *(const bf16x8*)&vts[vrh * 64 + ((0 + quad) ^ swh) * 8];
            const bf16x8 bh1 = *(const bf16x8*)&vts[vrh * 64 + ((4 + quad) ^ swh) * 8];
            const bf16x8 bl0 = *(const bf16x8*)&vts[vrl * 64 + ((0 + quad) ^ swl) * 8];
            const bf16x8 bl1 = *(const bf16x8*)&vts[vrl * 64 + ((4 + quad) ^ swl) * 8];
            __builtin_amdgcn_s_setprio(1);
#pragma unroll
            for (int mt = 0; mt < 4; mt++) {
                const int prow = mt * 16 + l15;
                const bf16x8 ph0 = *(const bf16x8*)&ps[prow * 152 + 0  + quad * 8];
                const bf16x8 ph1 = *(const bf16x8*)&ps[prow * 152 + 32 + quad * 8];
                const bf16x8 pl0 = *(const bf16x8*)&ps[prow * 152 + 64 + quad * 8];
                const bf16x8 pl1 = *(const bf16x8*)&ps[prow * 152 + 96 + quad * 8];
                f32x4 a = accpv[mt];
                a = __builtin_amdgcn_mfma_f32_16x16x32_bf16(ph0, bh0, a, 0, 0, 0);
                a = __builtin_amdgcn_mfma_f32_16x16x32_bf16(ph1, bh1, a, 0, 0, 0);
                a = __builtin_amdgcn_mfma_f32_16x16x32_bf16(ph0, bl0, a, 0, 0, 0);
                a = __builtin_amdgcn_mfma_f32_16x16x32_bf16(ph1, bl1, a, 0, 0, 0);
                a = __builtin_amdgcn_mfma_f32_16x16x32_bf16(pl0, bh0, a, 0, 0, 0);
                a = __builtin_amdgcn_mfma_f32_16x16x32_bf16(pl1, bh1, a, 0, 0, 0);
                accpv[mt] = a;
            }
            __builtin_amdgcn_s_setprio(0);
        }
    }
    // drain dummy K(8) + ALL fused stores (needed before in-place rescale)
    asm volatile("s_waitcnt vmcnt(0)" ::: "memory");

    __syncthreads();
    ssb[(tid & 3) * 64 + (tid >> 2)] = pacc;
    __syncthreads();
    if (tid < 64)
        ssum[tid] = ssb[tid] + ssb[64 + tid] + ssb[128 + tid] + ssb[192 + tid];
    __syncthreads();

    // ---- fused normalization (replaces norm_kernel): rescale this block's
    // own 64x512 fused slice in place; it is L2-hot (just written by this CU).
    {
        const int row = tid >> 2, c4 = tid & 3;
        const float inv = 1.f / ssum[row];
        float* fr = fused + ((size_t)hb * 512 + l0 + row) * 512 + c4 * 128;
#pragma unroll
        for (int jj = 0; jj < 32; jj++) {
            float4 v = *(float4*)(fr + jj * 4);
            v.x *= inv; v.y *= inv; v.z *= inv; v.w *= inv;
            *(float4*)(fr + jj * 4) = v;
        }
    }

#pragma unroll
    for (int mt = 0; mt < 4; mt++)
#pragma unroll
        for (int r2 = 0; r2 < 4; r2++) {
            const int lrow = mt * 16 + quad * 4 + r2;
            const float val = accpv[mt][r2] / ssum[lrow];
            const ushort_t hi = f2bf(val);
            const ushort_t lo = f2bf(val - bf2f(hi));
            const size_t obase = ((size_t)(b * 512 + l0 + lrow)) * K2_ + h * 64 + wv * 16 + l15;
            outp2[obase]       = hi;
            outp2[obase + D_]  = lo;
        }
}

// ---------------------------------------------------------------------------
extern "C" void kernel_launch(void* const* d_in, const int* in_sizes, int n_in,
                              void* d_out, int out_size, void* d_ws, size_t ws_size,
                              hipStream_t stream) {
    const float* q    = (const float*)d_in[0];
    const float* k    = (const float*)d_in[1];
    const float* v    = (const float*)d_in[2];
    const float* ploc = (const float*)d_in[3];
    const int*   mask = (const int*)  d_in[4];
    const float* Wq   = (const float*)d_in[5];
    const float* bq   = (const float*)d_in[6];
    const float* Wk   = (const float*)d_in[7];
    const float* bk   = (const float*)d_in[8];
    const float* Wv   = (const float*)d_in[9];
    const float* bv   = (const float*)d_in[10];
    const float* Wl   = (const float*)d_in[11];
    const float* bl   = (const float*)d_in[12];
    const float* Wf   = (const float*)d_in[13];
    const float* bf   = (const float*)d_in[14];

    // Arena. sig16 (50.33 MB) overlays [q2..WlT3 + gap] which are dead after
    // the projection GEMMs. WfT3 and later regions stay live.
    char* base = (char*)d_ws;
    short*    q2    = (short*)(base + 0);            // 12,582,912 B
    short*    k2    = (short*)(base + 12582912);
    short*    v2    = (short*)(base + 25165824);
    short*    WqT3  = (short*)(base + 37748736);     //  3,538,944 B
    short*    WkT3  = (short*)(base + 41287680);
    short*    WvT3  = (short*)(base + 44826624);
    short*    WlT3  = (short*)(base + 48365568);     //    589,824 B
    _Float16* sig16 = (_Float16*)(base + 0);         // 50,331,648 B overlay
    short*    WfT3  = (short*)(base + 50331648);
    ushort_t* qs2a  = (ushort_t*)(base + 53870592);  // 12,582,912 B
    ushort_t* ks2a  = (ushort_t*)(base + 66453504);
    ushort_t* vt2   = (ushort_t*)(base + 79036416);
    float*    swv   = (float*)(base + 91619328);     //  1,179,648 B
    float*    sums  = (float*)(base + 92798976);     //    196,608 B
    short*    outp2 = (short*)(base + 92995584);     // 12,582,912 B -> 105,578,496 total

    float* out   = (float*)d_out;
    float* fused = out + (size_t)4096 * D_;

    asplit_kernel<<<dim3(3, 4096, 3), 256, 0, stream>>>(q, k, v, q2, k2, v2);
    wsplit_kernel<<<dim3(12, 12, 5), 256, 0, stream>>>(
        Wq, Wk, Wv, Wl, Wf, WqT3, WkT3, WvT3, WlT3, WfT3);

    mfma_gemm<<<dim3(6, 32, 4), 256, 0, stream>>>(
        q2, k2, v2, WqT3, WkT3, WvT3, WlT3, WfT3,
        bq, bk, bv, bl, bf, outp2, qs2a, ks2a, vt2, swv, out, 0);

    sig_kernel<<<dim3(512, 8), 256, 0, stream>>>(ploc, swv, mask, sig16);

    attn_kernel<<<dim3(8, 8, 12), 256, 0, stream>>>(
        qs2a, ks2a, vt2, sig16, fused, (ushort_t*)outp2, sums);

    mfma_gemm<<<dim3(6, 32, 1), 256, 0, stream>>>(
        q2, k2, v2, WqT3, WkT3, WvT3, WlT3, WfT3,
        bq, bk, bv, bl, bf, outp2, qs2a, ks2a, vt2, swv, out, 4);
}

// Round 7
// 461.914 us; speedup vs baseline: 1.0127x; 1.0127x over previous
//
#include <hip/hip_runtime.h>
#include <hip/hip_bf16.h>

#define B_ 8
#define L_ 512
#define T_ 512
#define D_ 768
#define H_ 12
#define DH_ 64
#define SD_ 5
#define NSW_ 72   // H*(SD+1)
#define K2_ 1536  // split A:  [hi | lo]
#define K3_ 2304  // split W:  [hi | lo | hi]

typedef __attribute__((ext_vector_type(8))) short bf16x8;
typedef __attribute__((ext_vector_type(4))) float f32x4;
typedef unsigned short ushort_t;

__device__ __forceinline__ unsigned short f2bf(float x) {
    union { __hip_bfloat16 h; unsigned short u; } cv;
    cv.h = __float2bfloat16(x);
    return cv.u;
}
__device__ __forceinline__ float bf2f(unsigned short u) {
    union { unsigned short u; __hip_bfloat16 h; } cv;
    cv.u = u;
    return __bfloat162float(cv.h);
}

__device__ __forceinline__ void gload_lds16(const void* g, void* l) {
    __builtin_amdgcn_global_load_lds((const __attribute__((address_space(1))) void*)g,
                                     (__attribute__((address_space(3))) void*)l,
                                     16, 0, 0);
}

// ---------------------------------------------------------------------------
// Split fp32 activations -> A2 = [hi | lo] bf16, row-major [M][1536].
// ---------------------------------------------------------------------------
__global__ __launch_bounds__(256) void asplit_kernel(
    const float* __restrict__ q, const float* __restrict__ k, const float* __restrict__ v,
    short* __restrict__ q2, short* __restrict__ k2, short* __restrict__ v2)
{
    const int z = blockIdx.z;
    const float* A = (z == 0) ? q : (z == 1) ? k : v;
    short* O = (z == 0) ? q2 : (z == 1) ? k2 : v2;
    const int col = blockIdx.x * 256 + threadIdx.x;
    const int m   = blockIdx.y;
    if (col >= D_) return;
    const float a = A[(size_t)m * D_ + col];
    const unsigned short hi = f2bf(a);
    const unsigned short lo = f2bf(a - bf2f(hi));
    O[(size_t)m * K2_ + col]       = (short)hi;
    O[(size_t)m * K2_ + D_ + col]  = (short)lo;
}

// ---------------------------------------------------------------------------
// Transpose + split weights -> WT3 [Npad x 2304]: row n = [hi | lo | hi].
// ---------------------------------------------------------------------------
__global__ __launch_bounds__(256) void wsplit_kernel(
    const float* __restrict__ Wq, const float* __restrict__ Wk,
    const float* __restrict__ Wv, const float* __restrict__ Wl,
    const float* __restrict__ Wf,
    short* __restrict__ WqT3, short* __restrict__ WkT3, short* __restrict__ WvT3,
    short* __restrict__ WlT3, short* __restrict__ WfT3)
{
    const int z = blockIdx.z;
    const float* W; short* O; int Nw, Npad;
    if (z == 0)      { W = Wq; O = WqT3; Nw = D_;   Npad = 768; }
    else if (z == 1) { W = Wk; O = WkT3; Nw = D_;   Npad = 768; }
    else if (z == 2) { W = Wv; O = WvT3; Nw = D_;   Npad = 768; }
    else if (z == 3) { W = Wl; O = WlT3; Nw = NSW_; Npad = 128; }
    else             { W = Wf; O = WfT3; Nw = D_;   Npad = 768; }

    const int k0 = blockIdx.x * 64;
    const int n0 = blockIdx.y * 64;
    if (n0 >= Npad) return;

    __shared__ float sm[64][65];
    const int c  = threadIdx.x & 63;
    const int r4 = threadIdx.x >> 6;

#pragma unroll
    for (int i = 0; i < 16; i++) {
        const int r = i * 4 + r4;
        float val = 0.f;
        if (n0 + c < Nw) val = W[(size_t)(k0 + r) * Nw + n0 + c];
        sm[r][c] = val;
    }
    __syncthreads();

#pragma unroll
    for (int i = 0; i < 16; i++) {
        const int nl = i * 4 + r4;
        const int n  = n0 + nl;
        if (n >= Npad) continue;
        const float v = (n < Nw) ? sm[c][nl] : 0.f;
        const unsigned short hi = f2bf(v);
        const unsigned short lo = f2bf(v - bf2f(hi));
        const size_t rb = (size_t)n * K3_;
        O[rb + k0 + c]        = (short)hi;
        O[rb + 768 + k0 + c]  = (short)lo;
        O[rb + 1536 + k0 + c] = (short)hi;
    }
}

// ---------------------------------------------------------------------------
// MFMA GEMM (split-bf16, K=2304), BK=64, XOR-swizzled LDS, XCD block swizzle,
// 2-deep double-buffered pipeline with counted vmcnt; kk-split interleave:
// MFMA(kk0) overlaps the kk1 ds_reads (counted lgkmcnt) and MFMA(kk1)
// overlaps the next-tile staging. setprio(1) around MFMA clusters.
// ---------------------------------------------------------------------------
__global__ __launch_bounds__(256) void mfma_gemm(
    const short* __restrict__ q2, const short* __restrict__ k2, const short* __restrict__ v2,
    const short* __restrict__ WqT3, const short* __restrict__ WkT3,
    const short* __restrict__ WvT3, const short* __restrict__ WlT3,
    const short* __restrict__ WfT3,
    const float* __restrict__ bq, const float* __restrict__ bk,
    const float* __restrict__ bv, const float* __restrict__ bl,
    const float* __restrict__ bf,
    const short* __restrict__ outp2,
    ushort_t* __restrict__ qs2a, ushort_t* __restrict__ ks2a, ushort_t* __restrict__ vt2,
    float* __restrict__ swv, float* __restrict__ outf,
    int zoff)
{
    const int nwg   = gridDim.x * gridDim.y * gridDim.z;
    const int flat  = blockIdx.x + gridDim.x * (blockIdx.y + gridDim.y * blockIdx.z);
    const int flat2 = (flat & 7) * (nwg >> 3) + (flat >> 3);
    const int bxg   = flat2 % 6;
    const int rem   = flat2 / 6;
    const int byg   = rem & 31;
    const int bzg   = rem >> 5;

    const int z = zoff + bzg;
    const short* A2; const short* WT3; const float* bias;
    if (z == 0)      { A2 = q2;    WT3 = WqT3; bias = bq; }
    else if (z == 1) { A2 = k2;    WT3 = WkT3; bias = bk; }
    else if (z == 2) { A2 = v2;    WT3 = WvT3; bias = bv; }
    else if (z == 3) { A2 = q2;    WT3 = WlT3; bias = bl; }
    else             { A2 = outp2; WT3 = WfT3; bias = bf; }

    if (z == 3 && bxg != 0) return;

    const int m0 = byg * 128;
    const int n0 = bxg * 128;

    __shared__ __align__(16) short As[2][128 * 64];
    __shared__ __align__(16) short Bs[2][128 * 64];

    const int tid  = threadIdx.x;
    const int lane = tid & 63;
    const int wv_  = tid >> 6;
    const int wm   = (wv_ & 1) << 6;
    const int wn   = (wv_ >> 1) << 6;
    const int l15  = lane & 15;
    const int quad = lane >> 4;

    f32x4 acc[4][4] = {};

    const int NT = K3_ / 64;   // 36 K-steps

    auto stage = [&](int buf, int kb) {
        const int akb = (kb < 768) ? kb : kb - 768;  // A=[hi|lo]; W=[hi|lo|hi]
#pragma unroll
        for (int j = 0; j < 4; j++) {
            const int i = tid + 256 * j;
            const int r = i >> 3, c = i & 7, gc = c ^ (r & 7);
            gload_lds16(A2 + (size_t)(m0 + r) * K2_ + akb + gc * 8, &As[buf][i * 8]);
        }
#pragma unroll
        for (int j = 0; j < 4; j++) {
            const int i = tid + 256 * j;
            const int r = i >> 3, c = i & 7, gc = c ^ (r & 7);
            gload_lds16(WT3 + (size_t)(n0 + r) * K3_ + kb + gc * 8, &Bs[buf][i * 8]);
        }
    };

    stage(0, 0);
    stage(1, 64);

    int cur = 0;
    for (int t = 0; t < NT; ++t) {
        asm volatile("s_waitcnt vmcnt(8)" ::: "memory");
        __builtin_amdgcn_s_barrier();

        bf16x8 af[2][4], bfr[2][4];
        // kk0 read group first (order pinned so lgkmcnt(8) == "kk0 done")
#pragma unroll
        for (int tt = 0; tt < 4; tt++) {
            const int ar = wm + tt * 16 + l15;
            const int br = wn + tt * 16 + l15;
            af[0][tt]  = *(const bf16x8*)&As[cur][ar * 64 + (quad ^ (ar & 7)) * 8];
            bfr[0][tt] = *(const bf16x8*)&Bs[cur][br * 64 + (quad ^ (br & 7)) * 8];
        }
        __builtin_amdgcn_sched_barrier(0);
#pragma unroll
        for (int tt = 0; tt < 4; tt++) {
            const int ar = wm + tt * 16 + l15;
            const int br = wn + tt * 16 + l15;
            af[1][tt]  = *(const bf16x8*)&As[cur][ar * 64 + ((4 + quad) ^ (ar & 7)) * 8];
            bfr[1][tt] = *(const bf16x8*)&Bs[cur][br * 64 + ((4 + quad) ^ (br & 7)) * 8];
        }
        __builtin_amdgcn_sched_barrier(0);

        // kk0 MFMAs overlap the kk1 reads still in flight
        asm volatile("s_waitcnt lgkmcnt(8)" ::: "memory");
        __builtin_amdgcn_sched_barrier(0);
        __builtin_amdgcn_s_setprio(1);
#pragma unroll
        for (int mt = 0; mt < 4; mt++)
#pragma unroll
            for (int nt = 0; nt < 4; nt++)
                acc[mt][nt] = __builtin_amdgcn_mfma_f32_16x16x32_bf16(
                    af[0][mt], bfr[0][nt], acc[mt][nt], 0, 0, 0);
        __builtin_amdgcn_s_setprio(0);

        asm volatile("s_waitcnt lgkmcnt(0)" ::: "memory");
        __builtin_amdgcn_sched_barrier(0);
        __builtin_amdgcn_s_barrier();     // all waves' reads done -> buffer reusable

        const int kb2 = (t + 2 < NT) ? (t + 2) * 64 : 0;
        stage(cur, kb2);
        __builtin_amdgcn_sched_barrier(0);

        __builtin_amdgcn_s_setprio(1);
#pragma unroll
        for (int mt = 0; mt < 4; mt++)
#pragma unroll
            for (int nt = 0; nt < 4; nt++)
                acc[mt][nt] = __builtin_amdgcn_mfma_f32_16x16x32_bf16(
                    af[1][mt], bfr[1][nt], acc[mt][nt], 0, 0, 0);
        __builtin_amdgcn_s_setprio(0);
        cur ^= 1;
    }
    asm volatile("s_waitcnt vmcnt(0)" ::: "memory");

    if (z <= 2) {
        ushort_t* dst = (z == 0) ? qs2a : (z == 1) ? ks2a : vt2;
#pragma unroll
        for (int nt = 0; nt < 4; nt++) {
            const int col = n0 + wn + nt * 16 + l15;
            const int hh = col >> 6, dd = col & 63;
            const float bvv = bias[col];
#pragma unroll
            for (int mt = 0; mt < 4; mt++) {
                const int rowb = m0 + wm + mt * 16 + quad * 4;
                if (z < 2) {
#pragma unroll
                    for (int r = 0; r < 4; r++) {
                        const int gr = rowb + r;
                        const int bb = gr >> 9, ll = gr & 511;
                        const float x = acc[mt][nt][r] + bvv;
                        const ushort_t hi = f2bf(x);
                        const ushort_t lo = f2bf(x - bf2f(hi));
                        const size_t base = (((size_t)hh * B_ + bb) * 512 + ll) * 128 + dd;
                        dst[base]      = hi;
                        dst[base + 64] = lo;
                    }
                } else {
                    const int bb = rowb >> 9, tt = rowb & 511;
                    ushort_t hi4[4], lo4[4];
#pragma unroll
                    for (int r = 0; r < 4; r++) {
                        const float x = acc[mt][nt][r] + bvv;
                        hi4[r] = f2bf(x);
                        lo4[r] = f2bf(x - bf2f(hi4[r]));
                    }
                    const size_t base = (((size_t)hh * B_ + bb) * 128 + dd) * 512 + tt;
                    *(ushort4*)&dst[base]            = *(ushort4*)hi4;
                    *(ushort4*)&dst[base + 64 * 512] = *(ushort4*)lo4;
                }
            }
        }
    } else if (z == 3) {
#pragma unroll
        for (int nt = 0; nt < 4; nt++) {
            const int col = n0 + wn + nt * 16 + l15;
            if (col >= NSW_) continue;
            const float bvv = bias[col];
#pragma unroll
            for (int mt = 0; mt < 4; mt++) {
                const int row = m0 + wm + mt * 16 + quad * 4;
#pragma unroll
                for (int r = 0; r < 4; r++)
                    swv[(size_t)(row + r) * NSW_ + col] = acc[mt][nt][r] + bvv;
            }
        }
    } else {
#pragma unroll
        for (int nt = 0; nt < 4; nt++) {
            const int col = n0 + wn + nt * 16 + l15;
            const float bvv = bias[col];
#pragma unroll
            for (int mt = 0; mt < 4; mt++) {
                const int row = m0 + wm + mt * 16 + quad * 4;
#pragma unroll
                for (int r = 0; r < 4; r++)
                    outf[(size_t)(row + r) * D_ + col] = acc[mt][nt][r] + bvv;
            }
        }
    }
}

// ---------------------------------------------------------------------------
// sig16[h][b][l][t] = mask ? 0 : max(sigmoid(bias_h + w_h · ploc[b,l,t,:]), 1e-6)
// ---------------------------------------------------------------------------
__global__ __launch_bounds__(256) void sig_kernel(
    const float* __restrict__ ploc, const float* __restrict__ swv,
    const int* __restrict__ maskp, _Float16* __restrict__ sig16)
{
    const int b = blockIdx.y;
    const int l = blockIdx.x;
    const int tid = threadIdx.x;

    __shared__ float pls[512 * 5];
    __shared__ float sws[72];
    __shared__ int   msk[512];

    const float* src = ploc + (size_t)(b * 512 + l) * 512 * 5;
    for (int i = tid; i < 640; i += 256)
        *(float4*)&pls[i * 4] = *(const float4*)(src + i * 4);
    if (tid < 72) sws[tid] = swv[(size_t)(b * 512 + l) * NSW_ + tid];
    for (int i = tid; i < 512; i += 256) msk[i] = maskp[b * 512 + i];
    __syncthreads();

    for (int e = tid; e < H_ * 512; e += 256) {
        const int t  = e & 511;
        const int hh = e >> 9;
        float s = sws[hh * 6];
#pragma unroll
        for (int d = 0; d < SD_; d++) s += sws[hh * 6 + 1 + d] * pls[t * 5 + d];
        const float sig = msk[t] ? 0.f : fmaxf(1.f / (1.f + __expf(-s)), 1e-6f);
        sig16[(((size_t)hh * B_ + b) * 512 + l) * 512 + t] = (_Float16)sig;
    }
}

// ---------------------------------------------------------------------------
// MFMA attention v3 — pipelined (Q in regs, K dbuf counted vmcnt, V staged
// under QK), setprio around MFMA clusters. Normalization in separate kernel
// (fused in-place rescale measured -55us regression: fused slice not L2-hot).
// ---------------------------------------------------------------------------
__global__ __launch_bounds__(256) void attn_kernel(
    const ushort_t* __restrict__ qs2, const ushort_t* __restrict__ ks2,
    const ushort_t* __restrict__ vt2, const _Float16* __restrict__ sig16,
    float* __restrict__ fused, ushort_t* __restrict__ outp2,
    float* __restrict__ sums)
{
    // grid (8,8,12) = 768 blocks; bijective XCD swizzle, x (l-tile) fastest.
    const int flat  = blockIdx.x + 8 * (blockIdx.y + 8 * blockIdx.z);
    const int flat2 = (flat & 7) * 96 + (flat >> 3);
    const int h  = flat2 / 64;
    const int b  = (flat2 >> 3) & 7;
    const int l0 = (flat2 & 7) << 6;

    const int hb = h * B_ + b;
    const int tid  = threadIdx.x;
    const int lane = tid & 63;
    const int wv   = tid >> 6;
    const int l15  = lane & 15;
    const int quad = lane >> 4;

    __shared__ __align__(16) ushort_t ks[2][64 * 128];
    __shared__ __align__(16) ushort_t vts[128 * 64];
    __shared__ __align__(16) ushort_t ps[64 * 152];   // [l][hi 0-63 | lo 64-127 | pad]
    __shared__ float ssb[4 * 64];
    __shared__ float ssum[64];

    // Q fragments straight to registers
    bf16x8 qreg[4][4];
    {
        const ushort_t* qb = qs2 + ((size_t)hb * 512 + l0) * 128;
#pragma unroll
        for (int mt = 0; mt < 4; mt++) {
            const ushort_t* qr = qb + (size_t)(mt * 16 + l15) * 128 + quad * 8;
            qreg[mt][0] = *(const bf16x8*)(qr);
            qreg[mt][1] = *(const bf16x8*)(qr + 32);
            qreg[mt][2] = *(const bf16x8*)(qr + 64);
            qreg[mt][3] = *(const bf16x8*)(qr + 96);
        }
    }

    float pacc = 0.f;
    f32x4 accpv[4] = {};

    auto stageK = [&](int buf, int t0s) {
        const size_t kbase = ((size_t)hb * 512 + t0s) * 128;
#pragma unroll
        for (int j = 0; j < 4; j++) {
            const int i = tid + 256 * j;
            const int r = i >> 4, c = i & 15, gc = c ^ (r & 7);
            gload_lds16(ks2 + kbase + r * 128 + gc * 8, &ks[buf][i * 8]);
        }
    };
    auto stageV = [&](int t0s) {
        const size_t vbase = (size_t)hb * 128 * 512;
#pragma unroll
        for (int j = 0; j < 4; j++) {
            const int i = tid + 256 * j;
            const int r = i >> 3, c = i & 7, gc = c ^ (r & 7);
            gload_lds16(vt2 + vbase + (size_t)r * 512 + t0s + gc * 8, &vts[i * 8]);
        }
    };

    stageK(0, 0);

#pragma unroll 1
    for (int it = 0; it < 8; ++it) {
        const int t0  = it << 6;
        const int cur = it & 1;
        if (it == 0) asm volatile("s_waitcnt vmcnt(0)" ::: "memory");
        else         asm volatile("s_waitcnt vmcnt(4)" ::: "memory");
        __builtin_amdgcn_sched_barrier(0);
        __builtin_amdgcn_s_barrier();   // K(it) visible; prev-iter LDS reads done

        float sigv[4][4];
        {
            const _Float16* sgp = sig16 + (((size_t)hb * 512 + l0) * 512) + t0 + wv * 16 + l15;
#pragma unroll
            for (int mt = 0; mt < 4; mt++)
#pragma unroll
                for (int r2 = 0; r2 < 4; r2++)
                    sigv[mt][r2] = (float)sgp[(size_t)(mt * 16 + quad * 4 + r2) * 512];
        }
        __builtin_amdgcn_sched_barrier(0);
        stageV(t0);                                   // V(it): drained at mid-barrier
        stageK(cur ^ 1, (it < 7) ? t0 + 64 : 0);      // K(it+1): drained next iter-top
        __builtin_amdgcn_sched_barrier(0);

        // ---- QK ----
        f32x4 acq[4] = {};
        {
            const int trow = wv * 16 + l15;
            const int tsw  = trow & 7;
            const bf16x8 bk0 = *(const bf16x8*)&ks[cur][trow * 128 + ((0  + quad) ^ tsw) * 8];
            const bf16x8 bk1 = *(const bf16x8*)&ks[cur][trow * 128 + ((4  + quad) ^ tsw) * 8];
            const bf16x8 bk2 = *(const bf16x8*)&ks[cur][trow * 128 + ((8  + quad) ^ tsw) * 8];
            const bf16x8 bk3 = *(const bf16x8*)&ks[cur][trow * 128 + ((12 + quad) ^ tsw) * 8];
            __builtin_amdgcn_s_setprio(1);
#pragma unroll
            for (int mt = 0; mt < 4; mt++) {
                f32x4 a = acq[mt];
                a = __builtin_amdgcn_mfma_f32_16x16x32_bf16(qreg[mt][0], bk0, a, 0, 0, 0);
                a = __builtin_amdgcn_mfma_f32_16x16x32_bf16(qreg[mt][1], bk1, a, 0, 0, 0);
                a = __builtin_amdgcn_mfma_f32_16x16x32_bf16(qreg[mt][0], bk2, a, 0, 0, 0);
                a = __builtin_amdgcn_mfma_f32_16x16x32_bf16(qreg[mt][1], bk3, a, 0, 0, 0);
                a = __builtin_amdgcn_mfma_f32_16x16x32_bf16(qreg[mt][2], bk0, a, 0, 0, 0);
                a = __builtin_amdgcn_mfma_f32_16x16x32_bf16(qreg[mt][3], bk1, a, 0, 0, 0);
                acq[mt] = a;
            }
            __builtin_amdgcn_s_setprio(0);
        }

        // ---- p = sig * exp(qk/8), split to LDS ----
        {
            const int tcol = wv * 16 + l15;
#pragma unroll
            for (int mt = 0; mt < 4; mt++)
#pragma unroll
                for (int r2 = 0; r2 < 4; r2++) {
                    const int lrow = mt * 16 + quad * 4 + r2;
                    const float p  = sigv[mt][r2] * __expf(acq[mt][r2] * 0.125f);
                    const ushort_t hi = f2bf(p);
                    const ushort_t lo = f2bf(p - bf2f(hi));
                    ps[lrow * 152 + tcol]      = hi;
                    ps[lrow * 152 + 64 + tcol] = lo;
                }
        }
        asm volatile("s_waitcnt lgkmcnt(0) vmcnt(4)" ::: "memory");
        __builtin_amdgcn_sched_barrier(0);
        __builtin_amdgcn_s_barrier();

        // ---- fused store (b128 ps reads) + row-sum partials ----
        {
            const int row = tid >> 2, c4 = tid & 3;
            const bf16x8 h0 = *(const bf16x8*)&ps[row * 152 + c4 * 16];
            const bf16x8 h1 = *(const bf16x8*)&ps[row * 152 + c4 * 16 + 8];
            const bf16x8 g0 = *(const bf16x8*)&ps[row * 152 + 64 + c4 * 16];
            const bf16x8 g1 = *(const bf16x8*)&ps[row * 152 + 64 + c4 * 16 + 8];
            float vbuf[16];
            float s = 0.f;
#pragma unroll
            for (int jj = 0; jj < 8; jj++) {
                vbuf[jj]     = bf2f((ushort_t)h0[jj]) + bf2f((ushort_t)g0[jj]);
                vbuf[8 + jj] = bf2f((ushort_t)h1[jj]) + bf2f((ushort_t)g1[jj]);
                s += vbuf[jj] + vbuf[8 + jj];
            }
            pacc += s;
            float* dstf = fused + ((size_t)hb * 512 + l0 + row) * 512 + t0 + c4 * 16;
#pragma unroll
            for (int jj = 0; jj < 4; jj++)
                *(float4*)(dstf + jj * 4) = *(float4*)&vbuf[jj * 4];
        }

        // ---- PV ----
        {
            const int vrh = wv * 16 + l15;
            const int vrl = 64 + vrh;
            const int swh = vrh & 7, swl = vrl & 7;
            const bf16x8 bh0 = *(const bf16x8*)&vts[vrh * 64 + ((0 + quad) ^ swh) * 8];
            const bf16x8 bh1 = *(const bf16x8*)&vts[vrh * 64 + ((4 + quad) ^ swh) * 8];
            const bf16x8 bl0 = *(const bf16x8*)&vts[vrl * 64 + ((0 + quad) ^ swl) * 8];
            const bf16x8 bl1 = *(const bf16x8*)&vts[vrl * 64 + ((4 + quad) ^ swl) * 8];
            __builtin_amdgcn_s_setprio(1);
#pragma unroll
            for (int mt = 0; mt < 4; mt++) {
                const int prow = mt * 16 + l15;
                const bf16x8 ph0 = *(const bf16x8*)&ps[prow * 152 + 0  + quad * 8];
                const bf16x8 ph1 = *(const bf16x8*)&ps[prow * 152 + 32 + quad * 8];
                const bf16x8 pl0 = *(const bf16x8*)&ps[prow * 152 + 64 + quad * 8];
                const bf16x8 pl1 = *(const bf16x8*)&ps[prow * 152 + 96 + quad * 8];
                f32x4 a = accpv[mt];
                a = __builtin_amdgcn_mfma_f32_16x16x32_bf16(ph0, bh0, a, 0, 0, 0);
                a = __builtin_amdgcn_mfma_f32_16x16x32_bf16(ph1, bh1, a, 0, 0, 0);
                a = __builtin_amdgcn_mfma_f32_16x16x32_bf16(ph0, bl0, a, 0, 0, 0);
                a = __builtin_amdgcn_mfma_f32_16x16x32_bf16(ph1, bl1, a, 0, 0, 0);
                a = __builtin_amdgcn_mfma_f32_16x16x32_bf16(pl0, bh0, a, 0, 0, 0);
                a = __builtin_amdgcn_mfma_f32_16x16x32_bf16(pl1, bh1, a, 0, 0, 0);
                accpv[mt] = a;
            }
            __builtin_amdgcn_s_setprio(0);
        }
    }
    asm volatile("s_waitcnt vmcnt(0)" ::: "memory");   // drain dummy K(8)

    __syncthreads();
    ssb[(tid & 3) * 64 + (tid >> 2)] = pacc;
    __syncthreads();
    if (tid < 64) {
        const float s = ssb[tid] + ssb[64 + tid] + ssb[128 + tid] + ssb[192 + tid];
        ssum[tid] = s;
        sums[(size_t)hb * 512 + l0 + tid] = s;
    }
    __syncthreads();

#pragma unroll
    for (int mt = 0; mt < 4; mt++)
#pragma unroll
        for (int r2 = 0; r2 < 4; r2++) {
            const int lrow = mt * 16 + quad * 4 + r2;
            const float val = accpv[mt][r2] / ssum[lrow];
            const ushort_t hi = f2bf(val);
            const ushort_t lo = f2bf(val - bf2f(hi));
            const size_t obase = ((size_t)(b * 512 + l0 + lrow)) * K2_ + h * 64 + wv * 16 + l15;
            outp2[obase]       = hi;
            outp2[obase + D_]  = lo;
        }
}

// Scale fused_attn in place by 1/rowsum.
__global__ __launch_bounds__(256) void norm_kernel(
    float* __restrict__ fused, const float* __restrict__ sums)
{
    const int gi = blockIdx.x * 256 + threadIdx.x;
    float4* f4 = (float4*)fused;
    float4 v = f4[gi];
    const float inv = 1.f / sums[gi >> 7];
    v.x *= inv; v.y *= inv; v.z *= inv; v.w *= inv;
    f4[gi] = v;
}

// ---------------------------------------------------------------------------
extern "C" void kernel_launch(void* const* d_in, const int* in_sizes, int n_in,
                              void* d_out, int out_size, void* d_ws, size_t ws_size,
                              hipStream_t stream) {
    const float* q    = (const float*)d_in[0];
    const float* k    = (const float*)d_in[1];
    const float* v    = (const float*)d_in[2];
    const float* ploc = (const float*)d_in[3];
    const int*   mask = (const int*)  d_in[4];
    const float* Wq   = (const float*)d_in[5];
    const float* bq   = (const float*)d_in[6];
    const float* Wk   = (const float*)d_in[7];
    const float* bk   = (const float*)d_in[8];
    const float* Wv   = (const float*)d_in[9];
    const float* bv   = (const float*)d_in[10];
    const float* Wl   = (const float*)d_in[11];
    const float* bl   = (const float*)d_in[12];
    const float* Wf   = (const float*)d_in[13];
    const float* bf   = (const float*)d_in[14];

    // Arena. sig16 (50.33 MB) overlays [q2..WlT3 + gap] which are dead after
    // the projection GEMMs. WfT3 and later regions stay live.
    char* base = (char*)d_ws;
    short*    q2    = (short*)(base + 0);            // 12,582,912 B
    short*    k2    = (short*)(base + 12582912);
    short*    v2    = (short*)(base + 25165824);
    short*    WqT3  = (short*)(base + 37748736);     //  3,538,944 B
    short*    WkT3  = (short*)(base + 41287680);
    short*    WvT3  = (short*)(base + 44826624);
    short*    WlT3  = (short*)(base + 48365568);     //    589,824 B
    _Float16* sig16 = (_Float16*)(base + 0);         // 50,331,648 B overlay
    short*    WfT3  = (short*)(base + 50331648);
    ushort_t* qs2a  = (ushort_t*)(base + 53870592);  // 12,582,912 B
    ushort_t* ks2a  = (ushort_t*)(base + 66453504);
    ushort_t* vt2   = (ushort_t*)(base + 79036416);
    float*    swv   = (float*)(base + 91619328);     //  1,179,648 B
    float*    sums  = (float*)(base + 92798976);     //    196,608 B
    short*    outp2 = (short*)(base + 92995584);     // 12,582,912 B -> 105,578,496 total

    float* out   = (float*)d_out;
    float* fused = out + (size_t)4096 * D_;

    asplit_kernel<<<dim3(3, 4096, 3), 256, 0, stream>>>(q, k, v, q2, k2, v2);
    wsplit_kernel<<<dim3(12, 12, 5), 256, 0, stream>>>(
        Wq, Wk, Wv, Wl, Wf, WqT3, WkT3, WvT3, WlT3, WfT3);

    mfma_gemm<<<dim3(6, 32, 4), 256, 0, stream>>>(
        q2, k2, v2, WqT3, WkT3, WvT3, WlT3, WfT3,
        bq, bk, bv, bl, bf, outp2, qs2a, ks2a, vt2, swv, out, 0);

    sig_kernel<<<dim3(512, 8), 256, 0, stream>>>(ploc, swv, mask, sig16);

    attn_kernel<<<dim3(8, 8, 12), 256, 0, stream>>>(
        qs2a, ks2a, vt2, sig16, fused, (ushort_t*)outp2, sums);

    norm_kernel<<<dim3(24576), 256, 0, stream>>>(fused, sums);

    mfma_gemm<<<dim3(6, 32, 1), 256, 0, stream>>>(
        q2, k2, v2, WqT3, WkT3, WvT3, WlT3, WfT3,
        bq, bk, bv, bl, bf, outp2, qs2a, ks2a, vt2, swv, out, 4);
}

// Round 8
// 439.863 us; speedup vs baseline: 1.0634x; 1.0501x over previous
//
#include <hip/hip_runtime.h>
#include <hip/hip_bf16.h>

#define B_ 8
#define L_ 512
#define T_ 512
#define D_ 768
#define H_ 12
#define DH_ 64
#define SD_ 5
#define NSW_ 72   // H*(SD+1)
#define K2_ 1536  // split layout: [hi(768) | lo(768)] for activations AND weights

typedef __attribute__((ext_vector_type(8))) short bf16x8;
typedef __attribute__((ext_vector_type(4))) float f32x4;
typedef unsigned short ushort_t;

__device__ __forceinline__ unsigned short f2bf(float x) {
    union { __hip_bfloat16 h; unsigned short u; } cv;
    cv.h = __float2bfloat16(x);
    return cv.u;
}
__device__ __forceinline__ float bf2f(unsigned short u) {
    union { unsigned short u; __hip_bfloat16 h; } cv;
    cv.u = u;
    return __bfloat162float(cv.h);
}

__device__ __forceinline__ void gload_lds16(const void* g, void* l) {
    __builtin_amdgcn_global_load_lds((const __attribute__((address_space(1))) void*)g,
                                     (__attribute__((address_space(3))) void*)l,
                                     16, 0, 0);
}

// ---------------------------------------------------------------------------
// Split fp32 activations -> A2 = [hi | lo] bf16, row-major [M][1536].
// ---------------------------------------------------------------------------
__global__ __launch_bounds__(256) void asplit_kernel(
    const float* __restrict__ q, const float* __restrict__ k, const float* __restrict__ v,
    short* __restrict__ q2, short* __restrict__ k2, short* __restrict__ v2)
{
    const int z = blockIdx.z;
    const float* A = (z == 0) ? q : (z == 1) ? k : v;
    short* O = (z == 0) ? q2 : (z == 1) ? k2 : v2;
    const int col = blockIdx.x * 256 + threadIdx.x;
    const int m   = blockIdx.y;
    if (col >= D_) return;
    const float a = A[(size_t)m * D_ + col];
    const unsigned short hi = f2bf(a);
    const unsigned short lo = f2bf(a - bf2f(hi));
    O[(size_t)m * K2_ + col]       = (short)hi;
    O[(size_t)m * K2_ + D_ + col]  = (short)lo;
}

// ---------------------------------------------------------------------------
// Transpose + split weights -> WT2 [Npad x 1536]: row n = [hi | lo].
// ---------------------------------------------------------------------------
__global__ __launch_bounds__(256) void wsplit_kernel(
    const float* __restrict__ Wq, const float* __restrict__ Wk,
    const float* __restrict__ Wv, const float* __restrict__ Wl,
    const float* __restrict__ Wf,
    short* __restrict__ WqT2, short* __restrict__ WkT2, short* __restrict__ WvT2,
    short* __restrict__ WlT2, short* __restrict__ WfT2)
{
    const int z = blockIdx.z;
    const float* W; short* O; int Nw, Npad;
    if (z == 0)      { W = Wq; O = WqT2; Nw = D_;   Npad = 768; }
    else if (z == 1) { W = Wk; O = WkT2; Nw = D_;   Npad = 768; }
    else if (z == 2) { W = Wv; O = WvT2; Nw = D_;   Npad = 768; }
    else if (z == 3) { W = Wl; O = WlT2; Nw = NSW_; Npad = 128; }
    else             { W = Wf; O = WfT2; Nw = D_;   Npad = 768; }

    const int k0 = blockIdx.x * 64;
    const int n0 = blockIdx.y * 64;
    if (n0 >= Npad) return;

    __shared__ float sm[64][65];
    const int c  = threadIdx.x & 63;
    const int r4 = threadIdx.x >> 6;

#pragma unroll
    for (int i = 0; i < 16; i++) {
        const int r = i * 4 + r4;
        float val = 0.f;
        if (n0 + c < Nw) val = W[(size_t)(k0 + r) * Nw + n0 + c];
        sm[r][c] = val;
    }
    __syncthreads();

#pragma unroll
    for (int i = 0; i < 16; i++) {
        const int nl = i * 4 + r4;
        const int n  = n0 + nl;
        if (n >= Npad) continue;
        const float v = (n < Nw) ? sm[c][nl] : 0.f;
        const unsigned short hi = f2bf(v);
        const unsigned short lo = f2bf(v - bf2f(hi));
        const size_t rb = (size_t)n * K2_;
        O[rb + k0 + c]        = (short)hi;
        O[rb + 768 + k0 + c]  = (short)lo;
    }
}

// ---------------------------------------------------------------------------
// MFMA GEMM, split-bf16 3-term (hi.hi + hi.lo + lo.hi) computed per K-chunk
// from ONE staging of {A.hi, A.lo, W.hi, W.lo} — 786KB/block staged vs the
// old [hi|lo|hi] stream's 1180KB (kernel was staging-throughput-bound).
// BK=32 (x2 halves), XOR-swizzled LDS, XCD swizzle, 2-deep dbuf counted vmcnt.
// Epilogues per z:
//  z=0: qs2a [h][b][l][hi64|lo64]   z=1: ks2a [h][b][t][hi64|lo64]
//  z=2: vt2  [h][b][dd(hi) / 64+dd(lo)][t]   z=3: swv fp32 [4096][72]
//  z=4: out fp32 [4096][768]
// ---------------------------------------------------------------------------
__global__ __launch_bounds__(256) void mfma_gemm(
    const short* __restrict__ q2, const short* __restrict__ k2, const short* __restrict__ v2,
    const short* __restrict__ WqT2, const short* __restrict__ WkT2,
    const short* __restrict__ WvT2, const short* __restrict__ WlT2,
    const short* __restrict__ WfT2,
    const float* __restrict__ bq, const float* __restrict__ bk,
    const float* __restrict__ bv, const float* __restrict__ bl,
    const float* __restrict__ bf,
    const short* __restrict__ outp2,
    ushort_t* __restrict__ qs2a, ushort_t* __restrict__ ks2a, ushort_t* __restrict__ vt2,
    float* __restrict__ swv, float* __restrict__ outf,
    int zoff)
{
    const int nwg   = gridDim.x * gridDim.y * gridDim.z;
    const int flat  = blockIdx.x + gridDim.x * (blockIdx.y + gridDim.y * blockIdx.z);
    const int flat2 = (flat & 7) * (nwg >> 3) + (flat >> 3);
    const int bxg   = flat2 % 6;
    const int rem   = flat2 / 6;
    const int byg   = rem & 31;
    const int bzg   = rem >> 5;

    const int z = zoff + bzg;
    const short* A2; const short* WT2; const float* bias;
    if (z == 0)      { A2 = q2;    WT2 = WqT2; bias = bq; }
    else if (z == 1) { A2 = k2;    WT2 = WkT2; bias = bk; }
    else if (z == 2) { A2 = v2;    WT2 = WvT2; bias = bv; }
    else if (z == 3) { A2 = q2;    WT2 = WlT2; bias = bl; }
    else             { A2 = outp2; WT2 = WfT2; bias = bf; }

    if (z == 3 && bxg != 0) return;

    const int m0 = byg * 128;
    const int n0 = bxg * 128;

    // Per K-step buffer row = [hi(32) | lo(32)] shorts.
    __shared__ __align__(16) short As[2][128 * 64];
    __shared__ __align__(16) short Bs[2][128 * 64];

    const int tid  = threadIdx.x;
    const int lane = tid & 63;
    const int wv_  = tid >> 6;
    const int wm   = (wv_ & 1) << 6;
    const int wn   = (wv_ >> 1) << 6;
    const int l15  = lane & 15;
    const int quad = lane >> 4;

    f32x4 acc[4][4] = {};

    const int NT = 768 / 32;   // 24 K-steps

    // Stage one step: global chunk g<4 -> hi cols kb+g*8; g>=4 -> lo cols
    // 768+kb+(g-4)*8. Closed form col = kb + g*8 + (g>>2)*736.
    auto stage = [&](int buf, int kb) {
#pragma unroll
        for (int j = 0; j < 4; j++) {
            const int i = tid + 256 * j;
            const int r = i >> 3, c = i & 7, g = c ^ (r & 7);
            const int col = kb + g * 8 + (g >> 2) * 736;
            gload_lds16(A2 + (size_t)(m0 + r) * K2_ + col, &As[buf][i * 8]);
        }
#pragma unroll
        for (int j = 0; j < 4; j++) {
            const int i = tid + 256 * j;
            const int r = i >> 3, c = i & 7, g = c ^ (r & 7);
            const int col = kb + g * 8 + (g >> 2) * 736;
            gload_lds16(WT2 + (size_t)(n0 + r) * K2_ + col, &Bs[buf][i * 8]);
        }
    };

    stage(0, 0);
    stage(1, 32);

    int cur = 0;
    for (int t = 0; t < NT; ++t) {
        asm volatile("s_waitcnt vmcnt(8)" ::: "memory");
        __builtin_amdgcn_s_barrier();

        bf16x8 afh[4], bfh[4], afl[4], bfl[4];
        // hi group first (order pinned: lgkmcnt(8) == "hi group done")
#pragma unroll
        for (int tt = 0; tt < 4; tt++) {
            const int ar = wm + tt * 16 + l15;
            const int br = wn + tt * 16 + l15;
            afh[tt] = *(const bf16x8*)&As[cur][ar * 64 + (quad ^ (ar & 7)) * 8];
            bfh[tt] = *(const bf16x8*)&Bs[cur][br * 64 + (quad ^ (br & 7)) * 8];
        }
        __builtin_amdgcn_sched_barrier(0);
#pragma unroll
        for (int tt = 0; tt < 4; tt++) {
            const int ar = wm + tt * 16 + l15;
            const int br = wn + tt * 16 + l15;
            afl[tt] = *(const bf16x8*)&As[cur][ar * 64 + ((4 + quad) ^ (ar & 7)) * 8];
            bfl[tt] = *(const bf16x8*)&Bs[cur][br * 64 + ((4 + quad) ^ (br & 7)) * 8];
        }
        __builtin_amdgcn_sched_barrier(0);

        // term1 (hi.hi) overlaps the lo-group reads
        asm volatile("s_waitcnt lgkmcnt(8)" ::: "memory");
        __builtin_amdgcn_sched_barrier(0);
#pragma unroll
        for (int mt = 0; mt < 4; mt++)
#pragma unroll
            for (int nt = 0; nt < 4; nt++)
                acc[mt][nt] = __builtin_amdgcn_mfma_f32_16x16x32_bf16(
                    afh[mt], bfh[nt], acc[mt][nt], 0, 0, 0);

        asm volatile("s_waitcnt lgkmcnt(0)" ::: "memory");
        __builtin_amdgcn_sched_barrier(0);
        __builtin_amdgcn_s_barrier();     // all waves done reading -> buffer reusable

        const int kb2 = (t + 2 < NT) ? (t + 2) * 32 : 0;
        stage(cur, kb2);
        __builtin_amdgcn_sched_barrier(0);

        // terms 2+3 (hi.lo, lo.hi) overlap the staging issue
#pragma unroll
        for (int mt = 0; mt < 4; mt++)
#pragma unroll
            for (int nt = 0; nt < 4; nt++)
                acc[mt][nt] = __builtin_amdgcn_mfma_f32_16x16x32_bf16(
                    afh[mt], bfl[nt], acc[mt][nt], 0, 0, 0);
#pragma unroll
        for (int mt = 0; mt < 4; mt++)
#pragma unroll
            for (int nt = 0; nt < 4; nt++)
                acc[mt][nt] = __builtin_amdgcn_mfma_f32_16x16x32_bf16(
                    afl[mt], bfh[nt], acc[mt][nt], 0, 0, 0);
        cur ^= 1;
    }
    asm volatile("s_waitcnt vmcnt(0)" ::: "memory");

    if (z <= 2) {
        ushort_t* dst = (z == 0) ? qs2a : (z == 1) ? ks2a : vt2;
#pragma unroll
        for (int nt = 0; nt < 4; nt++) {
            const int col = n0 + wn + nt * 16 + l15;
            const int hh = col >> 6, dd = col & 63;
            const float bvv = bias[col];
#pragma unroll
            for (int mt = 0; mt < 4; mt++) {
                const int rowb = m0 + wm + mt * 16 + quad * 4;
                if (z < 2) {
#pragma unroll
                    for (int r = 0; r < 4; r++) {
                        const int gr = rowb + r;
                        const int bb = gr >> 9, ll = gr & 511;
                        const float x = acc[mt][nt][r] + bvv;
                        const ushort_t hi = f2bf(x);
                        const ushort_t lo = f2bf(x - bf2f(hi));
                        const size_t base = (((size_t)hh * B_ + bb) * 512 + ll) * 128 + dd;
                        dst[base]      = hi;
                        dst[base + 64] = lo;
                    }
                } else {
                    const int bb = rowb >> 9, tt = rowb & 511;
                    ushort_t hi4[4], lo4[4];
#pragma unroll
                    for (int r = 0; r < 4; r++) {
                        const float x = acc[mt][nt][r] + bvv;
                        hi4[r] = f2bf(x);
                        lo4[r] = f2bf(x - bf2f(hi4[r]));
                    }
                    const size_t base = (((size_t)hh * B_ + bb) * 128 + dd) * 512 + tt;
                    *(ushort4*)&dst[base]            = *(ushort4*)hi4;
                    *(ushort4*)&dst[base + 64 * 512] = *(ushort4*)lo4;
                }
            }
        }
    } else if (z == 3) {
#pragma unroll
        for (int nt = 0; nt < 4; nt++) {
            const int col = n0 + wn + nt * 16 + l15;
            if (col >= NSW_) continue;
            const float bvv = bias[col];
#pragma unroll
            for (int mt = 0; mt < 4; mt++) {
                const int row = m0 + wm + mt * 16 + quad * 4;
#pragma unroll
                for (int r = 0; r < 4; r++)
                    swv[(size_t)(row + r) * NSW_ + col] = acc[mt][nt][r] + bvv;
            }
        }
    } else {
#pragma unroll
        for (int nt = 0; nt < 4; nt++) {
            const int col = n0 + wn + nt * 16 + l15;
            const float bvv = bias[col];
#pragma unroll
            for (int mt = 0; mt < 4; mt++) {
                const int row = m0 + wm + mt * 16 + quad * 4;
#pragma unroll
                for (int r = 0; r < 4; r++)
                    outf[(size_t)(row + r) * D_ + col] = acc[mt][nt][r] + bvv;
            }
        }
    }
}

// ---------------------------------------------------------------------------
// sig16[h][b][l][t] = mask ? 0 : max(sigmoid(bias_h + w_h · ploc[b,l,t,:]), 1e-6)
// ---------------------------------------------------------------------------
__global__ __launch_bounds__(256) void sig_kernel(
    const float* __restrict__ ploc, const float* __restrict__ swv,
    const int* __restrict__ maskp, _Float16* __restrict__ sig16)
{
    const int b = blockIdx.y;
    const int l = blockIdx.x;
    const int tid = threadIdx.x;

    __shared__ float pls[512 * 5];
    __shared__ float sws[72];
    __shared__ int   msk[512];

    const float* src = ploc + (size_t)(b * 512 + l) * 512 * 5;
    for (int i = tid; i < 640; i += 256)
        *(float4*)&pls[i * 4] = *(const float4*)(src + i * 4);
    if (tid < 72) sws[tid] = swv[(size_t)(b * 512 + l) * NSW_ + tid];
    for (int i = tid; i < 512; i += 256) msk[i] = maskp[b * 512 + i];
    __syncthreads();

    for (int e = tid; e < H_ * 512; e += 256) {
        const int t  = e & 511;
        const int hh = e >> 9;
        float s = sws[hh * 6];
#pragma unroll
        for (int d = 0; d < SD_; d++) s += sws[hh * 6 + 1 + d] * pls[t * 5 + d];
        const float sig = msk[t] ? 0.f : fmaxf(1.f / (1.f + __expf(-s)), 1e-6f);
        sig16[(((size_t)hh * B_ + b) * 512 + l) * 512 + t] = (_Float16)sig;
    }
}

// ---------------------------------------------------------------------------
// MFMA attention — pipelined (Q in regs, K dbuf counted vmcnt, V staged under
// QK). No setprio (measured ~-20us on this barrier-lockstep structure, R7).
// ---------------------------------------------------------------------------
__global__ __launch_bounds__(256) void attn_kernel(
    const ushort_t* __restrict__ qs2, const ushort_t* __restrict__ ks2,
    const ushort_t* __restrict__ vt2, const _Float16* __restrict__ sig16,
    float* __restrict__ fused, ushort_t* __restrict__ outp2,
    float* __restrict__ sums)
{
    // grid (8,8,12) = 768 blocks; bijective XCD swizzle, x (l-tile) fastest.
    const int flat  = blockIdx.x + 8 * (blockIdx.y + 8 * blockIdx.z);
    const int flat2 = (flat & 7) * 96 + (flat >> 3);
    const int h  = flat2 / 64;
    const int b  = (flat2 >> 3) & 7;
    const int l0 = (flat2 & 7) << 6;

    const int hb = h * B_ + b;
    const int tid  = threadIdx.x;
    const int lane = tid & 63;
    const int wv   = tid >> 6;
    const int l15  = lane & 15;
    const int quad = lane >> 4;

    __shared__ __align__(16) ushort_t ks[2][64 * 128];
    __shared__ __align__(16) ushort_t vts[128 * 64];
    __shared__ __align__(16) ushort_t ps[64 * 152];   // [l][hi 0-63 | lo 64-127 | pad]
    __shared__ float ssb[4 * 64];
    __shared__ float ssum[64];

    // Q fragments straight to registers
    bf16x8 qreg[4][4];
    {
        const ushort_t* qb = qs2 + ((size_t)hb * 512 + l0) * 128;
#pragma unroll
        for (int mt = 0; mt < 4; mt++) {
            const ushort_t* qr = qb + (size_t)(mt * 16 + l15) * 128 + quad * 8;
            qreg[mt][0] = *(const bf16x8*)(qr);
            qreg[mt][1] = *(const bf16x8*)(qr + 32);
            qreg[mt][2] = *(const bf16x8*)(qr + 64);
            qreg[mt][3] = *(const bf16x8*)(qr + 96);
        }
    }

    float pacc = 0.f;
    f32x4 accpv[4] = {};

    auto stageK = [&](int buf, int t0s) {
        const size_t kbase = ((size_t)hb * 512 + t0s) * 128;
#pragma unroll
        for (int j = 0; j < 4; j++) {
            const int i = tid + 256 * j;
            const int r = i >> 4, c = i & 15, gc = c ^ (r & 7);
            gload_lds16(ks2 + kbase + r * 128 + gc * 8, &ks[buf][i * 8]);
        }
    };
    auto stageV = [&](int t0s) {
        const size_t vbase = (size_t)hb * 128 * 512;
#pragma unroll
        for (int j = 0; j < 4; j++) {
            const int i = tid + 256 * j;
            const int r = i >> 3, c = i & 7, gc = c ^ (r & 7);
            gload_lds16(vt2 + vbase + (size_t)r * 512 + t0s + gc * 8, &vts[i * 8]);
        }
    };

    stageK(0, 0);

#pragma unroll 1
    for (int it = 0; it < 8; ++it) {
        const int t0  = it << 6;
        const int cur = it & 1;
        if (it == 0) asm volatile("s_waitcnt vmcnt(0)" ::: "memory");
        else         asm volatile("s_waitcnt vmcnt(4)" ::: "memory");
        __builtin_amdgcn_sched_barrier(0);
        __builtin_amdgcn_s_barrier();   // K(it) visible; prev-iter LDS reads done

        float sigv[4][4];
        {
            const _Float16* sgp = sig16 + (((size_t)hb * 512 + l0) * 512) + t0 + wv * 16 + l15;
#pragma unroll
            for (int mt = 0; mt < 4; mt++)
#pragma unroll
                for (int r2 = 0; r2 < 4; r2++)
                    sigv[mt][r2] = (float)sgp[(size_t)(mt * 16 + quad * 4 + r2) * 512];
        }
        __builtin_amdgcn_sched_barrier(0);
        stageV(t0);                                   // V(it): drained at mid-barrier
        stageK(cur ^ 1, (it < 7) ? t0 + 64 : 0);      // K(it+1): drained next iter-top
        __builtin_amdgcn_sched_barrier(0);

        // ---- QK ----
        f32x4 acq[4] = {};
        {
            const int trow = wv * 16 + l15;
            const int tsw  = trow & 7;
            const bf16x8 bk0 = *(const bf16x8*)&ks[cur][trow * 128 + ((0  + quad) ^ tsw) * 8];
            const bf16x8 bk1 = *(const bf16x8*)&ks[cur][trow * 128 + ((4  + quad) ^ tsw) * 8];
            const bf16x8 bk2 = *(const bf16x8*)&ks[cur][trow * 128 + ((8  + quad) ^ tsw) * 8];
            const bf16x8 bk3 = *(const bf16x8*)&ks[cur][trow * 128 + ((12 + quad) ^ tsw) * 8];
#pragma unroll
            for (int mt = 0; mt < 4; mt++) {
                f32x4 a = acq[mt];
                a = __builtin_amdgcn_mfma_f32_16x16x32_bf16(qreg[mt][0], bk0, a, 0, 0, 0);
                a = __builtin_amdgcn_mfma_f32_16x16x32_bf16(qreg[mt][1], bk1, a, 0, 0, 0);
                a = __builtin_amdgcn_mfma_f32_16x16x32_bf16(qreg[mt][0], bk2, a, 0, 0, 0);
                a = __builtin_amdgcn_mfma_f32_16x16x32_bf16(qreg[mt][1], bk3, a, 0, 0, 0);
                a = __builtin_amdgcn_mfma_f32_16x16x32_bf16(qreg[mt][2], bk0, a, 0, 0, 0);
                a = __builtin_amdgcn_mfma_f32_16x16x32_bf16(qreg[mt][3], bk1, a, 0, 0, 0);
                acq[mt] = a;
            }
        }

        // ---- p = sig * exp(qk/8), split to LDS ----
        {
            const int tcol = wv * 16 + l15;
#pragma unroll
            for (int mt = 0; mt < 4; mt++)
#pragma unroll
                for (int r2 = 0; r2 < 4; r2++) {
                    const int lrow = mt * 16 + quad * 4 + r2;
                    const float p  = sigv[mt][r2] * __expf(acq[mt][r2] * 0.125f);
                    const ushort_t hi = f2bf(p);
                    const ushort_t lo = f2bf(p - bf2f(hi));
                    ps[lrow * 152 + tcol]      = hi;
                    ps[lrow * 152 + 64 + tcol] = lo;
                }
        }
        asm volatile("s_waitcnt lgkmcnt(0) vmcnt(4)" ::: "memory");
        __builtin_amdgcn_sched_barrier(0);
        __builtin_amdgcn_s_barrier();

        // ---- fused store (b128 ps reads) + row-sum partials ----
        {
            const int row = tid >> 2, c4 = tid & 3;
            const bf16x8 h0 = *(const bf16x8*)&ps[row * 152 + c4 * 16];
            const bf16x8 h1 = *(const bf16x8*)&ps[row * 152 + c4 * 16 + 8];
            const bf16x8 g0 = *(const bf16x8*)&ps[row * 152 + 64 + c4 * 16];
            const bf16x8 g1 = *(const bf16x8*)&ps[row * 152 + 64 + c4 * 16 + 8];
            float vbuf[16];
            float s = 0.f;
#pragma unroll
            for (int jj = 0; jj < 8; jj++) {
                vbuf[jj]     = bf2f((ushort_t)h0[jj]) + bf2f((ushort_t)g0[jj]);
                vbuf[8 + jj] = bf2f((ushort_t)h1[jj]) + bf2f((ushort_t)g1[jj]);
                s += vbuf[jj] + vbuf[8 + jj];
            }
            pacc += s;
            float* dstf = fused + ((size_t)hb * 512 + l0 + row) * 512 + t0 + c4 * 16;
#pragma unroll
            for (int jj = 0; jj < 4; jj++)
                *(float4*)(dstf + jj * 4) = *(float4*)&vbuf[jj * 4];
        }

        // ---- PV ----
        {
            const int vrh = wv * 16 + l15;
            const int vrl = 64 + vrh;
            const int swh = vrh & 7, swl = vrl & 7;
            const bf16x8 bh0 = *(const bf16x8*)&vts[vrh * 64 + ((0 + quad) ^ swh) * 8];
            const bf16x8 bh1 = *(const bf16x8*)&vts[vrh * 64 + ((4 + quad) ^ swh) * 8];
            const bf16x8 bl0 = *(const bf16x8*)&vts[vrl * 64 + ((0 + quad) ^ swl) * 8];
            const bf16x8 bl1 = *(const bf16x8*)&vts[vrl * 64 + ((4 + quad) ^ swl) * 8];
#pragma unroll
            for (int mt = 0; mt < 4; mt++) {
                const int prow = mt * 16 + l15;
                const bf16x8 ph0 = *(const bf16x8*)&ps[prow * 152 + 0  + quad * 8];
                const bf16x8 ph1 = *(const bf16x8*)&ps[prow * 152 + 32 + quad * 8];
                const bf16x8 pl0 = *(const bf16x8*)&ps[prow * 152 + 64 + quad * 8];
                const bf16x8 pl1 = *(const bf16x8*)&ps[prow * 152 + 96 + quad * 8];
                f32x4 a = accpv[mt];
                a = __builtin_amdgcn_mfma_f32_16x16x32_bf16(ph0, bh0, a, 0, 0, 0);
                a = __builtin_amdgcn_mfma_f32_16x16x32_bf16(ph1, bh1, a, 0, 0, 0);
                a = __builtin_amdgcn_mfma_f32_16x16x32_bf16(ph0, bl0, a, 0, 0, 0);
                a = __builtin_amdgcn_mfma_f32_16x16x32_bf16(ph1, bl1, a, 0, 0, 0);
                a = __builtin_amdgcn_mfma_f32_16x16x32_bf16(pl0, bh0, a, 0, 0, 0);
                a = __builtin_amdgcn_mfma_f32_16x16x32_bf16(pl1, bh1, a, 0, 0, 0);
                accpv[mt] = a;
            }
        }
    }
    asm volatile("s_waitcnt vmcnt(0)" ::: "memory");   // drain dummy K(8)

    __syncthreads();
    ssb[(tid & 3) * 64 + (tid >> 2)] = pacc;
    __syncthreads();
    if (tid < 64) {
        const float s = ssb[tid] + ssb[64 + tid] + ssb[128 + tid] + ssb[192 + tid];
        ssum[tid] = s;
        sums[(size_t)hb * 512 + l0 + tid] = s;
    }
    __syncthreads();

#pragma unroll
    for (int mt = 0; mt < 4; mt++)
#pragma unroll
        for (int r2 = 0; r2 < 4; r2++) {
            const int lrow = mt * 16 + quad * 4 + r2;
            const float val = accpv[mt][r2] / ssum[lrow];
            const ushort_t hi = f2bf(val);
            const ushort_t lo = f2bf(val - bf2f(hi));
            const size_t obase = ((size_t)(b * 512 + l0 + lrow)) * K2_ + h * 64 + wv * 16 + l15;
            outp2[obase]       = hi;
            outp2[obase + D_]  = lo;
        }
}

// Scale fused_attn in place by 1/rowsum.
__global__ __launch_bounds__(256) void norm_kernel(
    float* __restrict__ fused, const float* __restrict__ sums)
{
    const int gi = blockIdx.x * 256 + threadIdx.x;
    float4* f4 = (float4*)fused;
    float4 v = f4[gi];
    const float inv = 1.f / sums[gi >> 7];
    v.x *= inv; v.y *= inv; v.z *= inv; v.w *= inv;
    f4[gi] = v;
}

// ---------------------------------------------------------------------------
extern "C" void kernel_launch(void* const* d_in, const int* in_sizes, int n_in,
                              void* d_out, int out_size, void* d_ws, size_t ws_size,
                              hipStream_t stream) {
    const float* q    = (const float*)d_in[0];
    const float* k    = (const float*)d_in[1];
    const float* v    = (const float*)d_in[2];
    const float* ploc = (const float*)d_in[3];
    const int*   mask = (const int*)  d_in[4];
    const float* Wq   = (const float*)d_in[5];
    const float* bq   = (const float*)d_in[6];
    const float* Wk   = (const float*)d_in[7];
    const float* bk   = (const float*)d_in[8];
    const float* Wv   = (const float*)d_in[9];
    const float* bv   = (const float*)d_in[10];
    const float* Wl   = (const float*)d_in[11];
    const float* bl   = (const float*)d_in[12];
    const float* Wf   = (const float*)d_in[13];
    const float* bf   = (const float*)d_in[14];

    // Arena (offsets unchanged; W buffers now use only [hi|lo] = 2/3 of their
    // reserved space). sig16 overlays [q2..WlT2 + gap], dead after projections.
    char* base = (char*)d_ws;
    short*    q2    = (short*)(base + 0);            // 12,582,912 B
    short*    k2    = (short*)(base + 12582912);
    short*    v2    = (short*)(base + 25165824);
    short*    WqT2  = (short*)(base + 37748736);
    short*    WkT2  = (short*)(base + 41287680);
    short*    WvT2  = (short*)(base + 44826624);
    short*    WlT2  = (short*)(base + 48365568);
    _Float16* sig16 = (_Float16*)(base + 0);         // 50,331,648 B overlay
    short*    WfT2  = (short*)(base + 50331648);
    ushort_t* qs2a  = (ushort_t*)(base + 53870592);  // 12,582,912 B
    ushort_t* ks2a  = (ushort_t*)(base + 66453504);
    ushort_t* vt2   = (ushort_t*)(base + 79036416);
    float*    swv   = (float*)(base + 91619328);     //  1,179,648 B
    float*    sums  = (float*)(base + 92798976);     //    196,608 B
    short*    outp2 = (short*)(base + 92995584);     // 12,582,912 B -> 105,578,496 total

    float* out   = (float*)d_out;
    float* fused = out + (size_t)4096 * D_;

    asplit_kernel<<<dim3(3, 4096, 3), 256, 0, stream>>>(q, k, v, q2, k2, v2);
    wsplit_kernel<<<dim3(12, 12, 5), 256, 0, stream>>>(
        Wq, Wk, Wv, Wl, Wf, WqT2, WkT2, WvT2, WlT2, WfT2);

    mfma_gemm<<<dim3(6, 32, 4), 256, 0, stream>>>(
        q2, k2, v2, WqT2, WkT2, WvT2, WlT2, WfT2,
        bq, bk, bv, bl, bf, outp2, qs2a, ks2a, vt2, swv, out, 0);

    sig_kernel<<<dim3(512, 8), 256, 0, stream>>>(ploc, swv, mask, sig16);

    attn_kernel<<<dim3(8, 8, 12), 256, 0, stream>>>(
        qs2a, ks2a, vt2, sig16, fused, (ushort_t*)outp2, sums);

    norm_kernel<<<dim3(24576), 256, 0, stream>>>(fused, sums);

    mfma_gemm<<<dim3(6, 32, 1), 256, 0, stream>>>(
        q2, k2, v2, WqT2, WkT2, WvT2, WlT2, WfT2,
        bq, bk, bv, bl, bf, outp2, qs2a, ks2a, vt2, swv, out, 4);
}

// Round 10
// 439.683 us; speedup vs baseline: 1.0639x; 1.0004x over previous
//
#include <hip/hip_runtime.h>
#include <hip/hip_bf16.h>

#define B_ 8
#define L_ 512
#define T_ 512
#define D_ 768
#define H_ 12
#define DH_ 64
#define SD_ 5
#define NSW_ 72   // H*(SD+1)
#define K2_ 1536  // split layout: [hi(768) | lo(768)] for activations AND weights

typedef __attribute__((ext_vector_type(8))) short bf16x8;
typedef __attribute__((ext_vector_type(4))) float f32x4;
typedef unsigned short ushort_t;

__device__ __forceinline__ unsigned short f2bf(float x) {
    union { __hip_bfloat16 h; unsigned short u; } cv;
    cv.h = __float2bfloat16(x);
    return cv.u;
}
__device__ __forceinline__ float bf2f(unsigned short u) {
    union { unsigned short u; __hip_bfloat16 h; } cv;
    cv.u = u;
    return __bfloat162float(cv.h);
}

__device__ __forceinline__ void gload_lds16(const void* g, void* l) {
    __builtin_amdgcn_global_load_lds((const __attribute__((address_space(1))) void*)g,
                                     (__attribute__((address_space(3))) void*)l,
                                     16, 0, 0);
}

// ---------------------------------------------------------------------------
// Split fp32 activations -> A2 = [hi | lo] bf16, row-major [M][1536].
// ---------------------------------------------------------------------------
__global__ __launch_bounds__(256) void asplit_kernel(
    const float* __restrict__ q, const float* __restrict__ k, const float* __restrict__ v,
    short* __restrict__ q2, short* __restrict__ k2, short* __restrict__ v2)
{
    const int z = blockIdx.z;
    const float* A = (z == 0) ? q : (z == 1) ? k : v;
    short* O = (z == 0) ? q2 : (z == 1) ? k2 : v2;
    const int col = blockIdx.x * 256 + threadIdx.x;
    const int m   = blockIdx.y;
    if (col >= D_) return;
    const float a = A[(size_t)m * D_ + col];
    const unsigned short hi = f2bf(a);
    const unsigned short lo = f2bf(a - bf2f(hi));
    O[(size_t)m * K2_ + col]       = (short)hi;
    O[(size_t)m * K2_ + D_ + col]  = (short)lo;
}

// ---------------------------------------------------------------------------
// Transpose + split weights -> WT2 [Npad x 1536]: row n = [hi | lo].
// ---------------------------------------------------------------------------
__global__ __launch_bounds__(256) void wsplit_kernel(
    const float* __restrict__ Wq, const float* __restrict__ Wk,
    const float* __restrict__ Wv, const float* __restrict__ Wl,
    const float* __restrict__ Wf,
    short* __restrict__ WqT2, short* __restrict__ WkT2, short* __restrict__ WvT2,
    short* __restrict__ WlT2, short* __restrict__ WfT2)
{
    const int z = blockIdx.z;
    const float* W; short* O; int Nw, Npad;
    if (z == 0)      { W = Wq; O = WqT2; Nw = D_;   Npad = 768; }
    else if (z == 1) { W = Wk; O = WkT2; Nw = D_;   Npad = 768; }
    else if (z == 2) { W = Wv; O = WvT2; Nw = D_;   Npad = 768; }
    else if (z == 3) { W = Wl; O = WlT2; Nw = NSW_; Npad = 128; }
    else             { W = Wf; O = WfT2; Nw = D_;   Npad = 768; }

    const int k0 = blockIdx.x * 64;
    const int n0 = blockIdx.y * 64;
    if (n0 >= Npad) return;

    __shared__ float sm[64][65];
    const int c  = threadIdx.x & 63;
    const int r4 = threadIdx.x >> 6;

#pragma unroll
    for (int i = 0; i < 16; i++) {
        const int r = i * 4 + r4;
        float val = 0.f;
        if (n0 + c < Nw) val = W[(size_t)(k0 + r) * Nw + n0 + c];
        sm[r][c] = val;
    }
    __syncthreads();

#pragma unroll
    for (int i = 0; i < 16; i++) {
        const int nl = i * 4 + r4;
        const int n  = n0 + nl;
        if (n >= Npad) continue;
        const float v = (n < Nw) ? sm[c][nl] : 0.f;
        const unsigned short hi = f2bf(v);
        const unsigned short lo = f2bf(v - bf2f(hi));
        const size_t rb = (size_t)n * K2_;
        O[rb + k0 + c]        = (short)hi;
        O[rb + 768 + k0 + c]  = (short)lo;
    }
}

// ---------------------------------------------------------------------------
// MFMA GEMM, split-bf16 3-term from ONE staging of {A.hi,A.lo,W.hi,W.lo}.
// BK=32, XOR-swizzled LDS, XCD swizzle, 2-deep dbuf counted vmcnt.
// (LDS-pipe-throughput-bound at ~18.5% MfmaUtil — structural for this tile.)
// ---------------------------------------------------------------------------
__global__ __launch_bounds__(256) void mfma_gemm(
    const short* __restrict__ q2, const short* __restrict__ k2, const short* __restrict__ v2,
    const short* __restrict__ WqT2, const short* __restrict__ WkT2,
    const short* __restrict__ WvT2, const short* __restrict__ WlT2,
    const short* __restrict__ WfT2,
    const float* __restrict__ bq, const float* __restrict__ bk,
    const float* __restrict__ bv, const float* __restrict__ bl,
    const float* __restrict__ bf,
    const short* __restrict__ outp2,
    ushort_t* __restrict__ qs2a, ushort_t* __restrict__ ks2a, ushort_t* __restrict__ vt2,
    float* __restrict__ swv, float* __restrict__ outf,
    int zoff)
{
    const int nwg   = gridDim.x * gridDim.y * gridDim.z;
    const int flat  = blockIdx.x + gridDim.x * (blockIdx.y + gridDim.y * blockIdx.z);
    const int flat2 = (flat & 7) * (nwg >> 3) + (flat >> 3);
    const int bxg   = flat2 % 6;
    const int rem   = flat2 / 6;
    const int byg   = rem & 31;
    const int bzg   = rem >> 5;

    const int z = zoff + bzg;
    const short* A2; const short* WT2; const float* bias;
    if (z == 0)      { A2 = q2;    WT2 = WqT2; bias = bq; }
    else if (z == 1) { A2 = k2;    WT2 = WkT2; bias = bk; }
    else if (z == 2) { A2 = v2;    WT2 = WvT2; bias = bv; }
    else if (z == 3) { A2 = q2;    WT2 = WlT2; bias = bl; }
    else             { A2 = outp2; WT2 = WfT2; bias = bf; }

    if (z == 3 && bxg != 0) return;

    const int m0 = byg * 128;
    const int n0 = bxg * 128;

    __shared__ __align__(16) short As[2][128 * 64];
    __shared__ __align__(16) short Bs[2][128 * 64];

    const int tid  = threadIdx.x;
    const int lane = tid & 63;
    const int wv_  = tid >> 6;
    const int wm   = (wv_ & 1) << 6;
    const int wn   = (wv_ >> 1) << 6;
    const int l15  = lane & 15;
    const int quad = lane >> 4;

    f32x4 acc[4][4] = {};

    const int NT = 768 / 32;   // 24 K-steps

    auto stage = [&](int buf, int kb) {
#pragma unroll
        for (int j = 0; j < 4; j++) {
            const int i = tid + 256 * j;
            const int r = i >> 3, c = i & 7, g = c ^ (r & 7);
            const int col = kb + g * 8 + (g >> 2) * 736;
            gload_lds16(A2 + (size_t)(m0 + r) * K2_ + col, &As[buf][i * 8]);
        }
#pragma unroll
        for (int j = 0; j < 4; j++) {
            const int i = tid + 256 * j;
            const int r = i >> 3, c = i & 7, g = c ^ (r & 7);
            const int col = kb + g * 8 + (g >> 2) * 736;
            gload_lds16(WT2 + (size_t)(n0 + r) * K2_ + col, &Bs[buf][i * 8]);
        }
    };

    stage(0, 0);
    stage(1, 32);

    int cur = 0;
    for (int t = 0; t < NT; ++t) {
        asm volatile("s_waitcnt vmcnt(8)" ::: "memory");
        __builtin_amdgcn_s_barrier();

        bf16x8 afh[4], bfh[4], afl[4], bfl[4];
#pragma unroll
        for (int tt = 0; tt < 4; tt++) {
            const int ar = wm + tt * 16 + l15;
            const int br = wn + tt * 16 + l15;
            afh[tt] = *(const bf16x8*)&As[cur][ar * 64 + (quad ^ (ar & 7)) * 8];
            bfh[tt] = *(const bf16x8*)&Bs[cur][br * 64 + (quad ^ (br & 7)) * 8];
        }
        __builtin_amdgcn_sched_barrier(0);
#pragma unroll
        for (int tt = 0; tt < 4; tt++) {
            const int ar = wm + tt * 16 + l15;
            const int br = wn + tt * 16 + l15;
            afl[tt] = *(const bf16x8*)&As[cur][ar * 64 + ((4 + quad) ^ (ar & 7)) * 8];
            bfl[tt] = *(const bf16x8*)&Bs[cur][br * 64 + ((4 + quad) ^ (br & 7)) * 8];
        }
        __builtin_amdgcn_sched_barrier(0);

        asm volatile("s_waitcnt lgkmcnt(8)" ::: "memory");
        __builtin_amdgcn_sched_barrier(0);
#pragma unroll
        for (int mt = 0; mt < 4; mt++)
#pragma unroll
            for (int nt = 0; nt < 4; nt++)
                acc[mt][nt] = __builtin_amdgcn_mfma_f32_16x16x32_bf16(
                    afh[mt], bfh[nt], acc[mt][nt], 0, 0, 0);

        asm volatile("s_waitcnt lgkmcnt(0)" ::: "memory");
        __builtin_amdgcn_sched_barrier(0);
        __builtin_amdgcn_s_barrier();

        const int kb2 = (t + 2 < NT) ? (t + 2) * 32 : 0;
        stage(cur, kb2);
        __builtin_amdgcn_sched_barrier(0);

#pragma unroll
        for (int mt = 0; mt < 4; mt++)
#pragma unroll
            for (int nt = 0; nt < 4; nt++)
                acc[mt][nt] = __builtin_amdgcn_mfma_f32_16x16x32_bf16(
                    afh[mt], bfl[nt], acc[mt][nt], 0, 0, 0);
#pragma unroll
        for (int mt = 0; mt < 4; mt++)
#pragma unroll
            for (int nt = 0; nt < 4; nt++)
                acc[mt][nt] = __builtin_amdgcn_mfma_f32_16x16x32_bf16(
                    afl[mt], bfh[nt], acc[mt][nt], 0, 0, 0);
        cur ^= 1;
    }
    asm volatile("s_waitcnt vmcnt(0)" ::: "memory");

    if (z <= 2) {
        ushort_t* dst = (z == 0) ? qs2a : (z == 1) ? ks2a : vt2;
#pragma unroll
        for (int nt = 0; nt < 4; nt++) {
            const int col = n0 + wn + nt * 16 + l15;
            const int hh = col >> 6, dd = col & 63;
            const float bvv = bias[col];
#pragma unroll
            for (int mt = 0; mt < 4; mt++) {
                const int rowb = m0 + wm + mt * 16 + quad * 4;
                if (z < 2) {
#pragma unroll
                    for (int r = 0; r < 4; r++) {
                        const int gr = rowb + r;
                        const int bb = gr >> 9, ll = gr & 511;
                        const float x = acc[mt][nt][r] + bvv;
                        const ushort_t hi = f2bf(x);
                        const ushort_t lo = f2bf(x - bf2f(hi));
                        const size_t base = (((size_t)hh * B_ + bb) * 512 + ll) * 128 + dd;
                        dst[base]      = hi;
                        dst[base + 64] = lo;
                    }
                } else {
                    const int bb = rowb >> 9, tt = rowb & 511;
                    ushort_t hi4[4], lo4[4];
#pragma unroll
                    for (int r = 0; r < 4; r++) {
                        const float x = acc[mt][nt][r] + bvv;
                        hi4[r] = f2bf(x);
                        lo4[r] = f2bf(x - bf2f(hi4[r]));
                    }
                    const size_t base = (((size_t)hh * B_ + bb) * 128 + dd) * 512 + tt;
                    *(ushort4*)&dst[base]            = *(ushort4*)hi4;
                    *(ushort4*)&dst[base + 64 * 512] = *(ushort4*)lo4;
                }
            }
        }
    } else if (z == 3) {
#pragma unroll
        for (int nt = 0; nt < 4; nt++) {
            const int col = n0 + wn + nt * 16 + l15;
            if (col >= NSW_) continue;
            const float bvv = bias[col];
#pragma unroll
            for (int mt = 0; mt < 4; mt++) {
                const int row = m0 + wm + mt * 16 + quad * 4;
#pragma unroll
                for (int r = 0; r < 4; r++)
                    swv[(size_t)(row + r) * NSW_ + col] = acc[mt][nt][r] + bvv;
            }
        }
    } else {
#pragma unroll
        for (int nt = 0; nt < 4; nt++) {
            const int col = n0 + wn + nt * 16 + l15;
            const float bvv = bias[col];
#pragma unroll
            for (int mt = 0; mt < 4; mt++) {
                const int row = m0 + wm + mt * 16 + quad * 4;
#pragma unroll
                for (int r = 0; r < 4; r++)
                    outf[(size_t)(row + r) * D_ + col] = acc[mt][nt][r] + bvv;
            }
        }
    }
}

// ---------------------------------------------------------------------------
// sig16[h][b][l][t] = mask ? 0 : max(sigmoid(bias_h + w_h · ploc[b,l,t,:]), 1e-6)
// ---------------------------------------------------------------------------
__global__ __launch_bounds__(256) void sig_kernel(
    const float* __restrict__ ploc, const float* __restrict__ swv,
    const int* __restrict__ maskp, _Float16* __restrict__ sig16)
{
    const int b = blockIdx.y;
    const int l = blockIdx.x;
    const int tid = threadIdx.x;

    __shared__ float pls[512 * 5];
    __shared__ float sws[72];
    __shared__ int   msk[512];

    const float* src = ploc + (size_t)(b * 512 + l) * 512 * 5;
    for (int i = tid; i < 640; i += 256)
        *(float4*)&pls[i * 4] = *(const float4*)(src + i * 4);
    if (tid < 72) sws[tid] = swv[(size_t)(b * 512 + l) * NSW_ + tid];
    for (int i = tid; i < 512; i += 256) msk[i] = maskp[b * 512 + i];
    __syncthreads();

    for (int e = tid; e < H_ * 512; e += 256) {
        const int t  = e & 511;
        const int hh = e >> 9;
        float s = sws[hh * 6];
#pragma unroll
        for (int d = 0; d < SD_; d++) s += sws[hh * 6 + 1 + d] * pls[t * 5 + d];
        const float sig = msk[t] ? 0.f : fmaxf(1.f / (1.f + __expf(-s)), 1e-6f);
        sig16[(((size_t)hh * B_ + b) * 512 + l) * 512 + t] = (_Float16)sig;
    }
}

// ---------------------------------------------------------------------------
// MFMA attention v4 — Q in regs, K dbuf (counted vmcnt), V DIRECT-TO-REGISTER
// (removes vts LDS staging: -33% LDS traffic; V slice is XCD-L2-hot).
// shfl-based row-sum reduce (no ssb) -> LDS 52.4KB -> 3 blocks/CU.
// ---------------------------------------------------------------------------
__global__ __launch_bounds__(256) void attn_kernel(
    const ushort_t* __restrict__ qs2, const ushort_t* __restrict__ ks2,
    const ushort_t* __restrict__ vt2, const _Float16* __restrict__ sig16,
    float* __restrict__ fused, ushort_t* __restrict__ outp2,
    float* __restrict__ sums)
{
    // grid (8,8,12) = 768 blocks; bijective XCD swizzle, x (l-tile) fastest.
    const int flat  = blockIdx.x + 8 * (blockIdx.y + 8 * blockIdx.z);
    const int flat2 = (flat & 7) * 96 + (flat >> 3);
    const int h  = flat2 / 64;
    const int b  = (flat2 >> 3) & 7;
    const int l0 = (flat2 & 7) << 6;

    const int hb = h * B_ + b;
    const int tid  = threadIdx.x;
    const int lane = tid & 63;
    const int wv   = tid >> 6;
    const int l15  = lane & 15;
    const int quad = lane >> 4;

    __shared__ __align__(16) ushort_t ks[2][64 * 128];
    __shared__ __align__(16) ushort_t ps[64 * 152];   // [l][hi 0-63 | lo 64-127 | pad]
    __shared__ float ssum[64];

    // Q fragments straight to registers
    bf16x8 qreg[4][4];
    {
        const ushort_t* qb = qs2 + ((size_t)hb * 512 + l0) * 128;
#pragma unroll
        for (int mt = 0; mt < 4; mt++) {
            const ushort_t* qr = qb + (size_t)(mt * 16 + l15) * 128 + quad * 8;
            qreg[mt][0] = *(const bf16x8*)(qr);
            qreg[mt][1] = *(const bf16x8*)(qr + 32);
            qreg[mt][2] = *(const bf16x8*)(qr + 64);
            qreg[mt][3] = *(const bf16x8*)(qr + 96);
        }
    }

    float pacc = 0.f;
    f32x4 accpv[4] = {};

    auto stageK = [&](int buf, int t0s) {
        const size_t kbase = ((size_t)hb * 512 + t0s) * 128;
#pragma unroll
        for (int j = 0; j < 4; j++) {
            const int i = tid + 256 * j;
            const int r = i >> 4, c = i & 15, gc = c ^ (r & 7);
            gload_lds16(ks2 + kbase + r * 128 + gc * 8, &ks[buf][i * 8]);
        }
    };

    // V^T base for this lane's d-rows (hi: vrh, lo: 64+vrh)
    const ushort_t* vrow = vt2 + ((size_t)hb * 128 + (wv * 16 + l15)) * 512;

    stageK(0, 0);

#pragma unroll 1
    for (int it = 0; it < 8; ++it) {
        const int t0  = it << 6;
        const int cur = it & 1;
        if (it == 0) asm volatile("s_waitcnt vmcnt(0)" ::: "memory");
        else         asm volatile("s_waitcnt vmcnt(4)" ::: "memory");
        __builtin_amdgcn_sched_barrier(0);
        __builtin_amdgcn_s_barrier();   // K(it) visible; prev-iter LDS reads done

        float sigv[4][4];
        {
            const _Float16* sgp = sig16 + (((size_t)hb * 512 + l0) * 512) + t0 + wv * 16 + l15;
#pragma unroll
            for (int mt = 0; mt < 4; mt++)
#pragma unroll
                for (int r2 = 0; r2 < 4; r2++)
                    sigv[mt][r2] = (float)sgp[(size_t)(mt * 16 + quad * 4 + r2) * 512];
        }
        __builtin_amdgcn_sched_barrier(0);
        // V fragments direct to registers (compiler inserts the use-waits)
        const bf16x8 bh0 = *(const bf16x8*)(vrow + t0 + quad * 8);
        const bf16x8 bh1 = *(const bf16x8*)(vrow + t0 + 32 + quad * 8);
        const bf16x8 bl0 = *(const bf16x8*)(vrow + 64 * 512 + t0 + quad * 8);
        const bf16x8 bl1 = *(const bf16x8*)(vrow + 64 * 512 + t0 + 32 + quad * 8);
        __builtin_amdgcn_sched_barrier(0);
        stageK(cur ^ 1, (it < 7) ? t0 + 64 : 0);      // K(it+1): drained next iter-top
        __builtin_amdgcn_sched_barrier(0);

        // ---- QK ----
        f32x4 acq[4] = {};
        {
            const int trow = wv * 16 + l15;
            const int tsw  = trow & 7;
            const bf16x8 bk0 = *(const bf16x8*)&ks[cur][trow * 128 + ((0  + quad) ^ tsw) * 8];
            const bf16x8 bk1 = *(const bf16x8*)&ks[cur][trow * 128 + ((4  + quad) ^ tsw) * 8];
            const bf16x8 bk2 = *(const bf16x8*)&ks[cur][trow * 128 + ((8  + quad) ^ tsw) * 8];
            const bf16x8 bk3 = *(const bf16x8*)&ks[cur][trow * 128 + ((12 + quad) ^ tsw) * 8];
#pragma unroll
            for (int mt = 0; mt < 4; mt++) {
                f32x4 a = acq[mt];
                a = __builtin_amdgcn_mfma_f32_16x16x32_bf16(qreg[mt][0], bk0, a, 0, 0, 0);
                a = __builtin_amdgcn_mfma_f32_16x16x32_bf16(qreg[mt][1], bk1, a, 0, 0, 0);
                a = __builtin_amdgcn_mfma_f32_16x16x32_bf16(qreg[mt][0], bk2, a, 0, 0, 0);
                a = __builtin_amdgcn_mfma_f32_16x16x32_bf16(qreg[mt][1], bk3, a, 0, 0, 0);
                a = __builtin_amdgcn_mfma_f32_16x16x32_bf16(qreg[mt][2], bk0, a, 0, 0, 0);
                a = __builtin_amdgcn_mfma_f32_16x16x32_bf16(qreg[mt][3], bk1, a, 0, 0, 0);
                acq[mt] = a;
            }
        }

        // ---- p = sig * exp(qk/8), split to LDS ----
        {
            const int tcol = wv * 16 + l15;
#pragma unroll
            for (int mt = 0; mt < 4; mt++)
#pragma unroll
                for (int r2 = 0; r2 < 4; r2++) {
                    const int lrow = mt * 16 + quad * 4 + r2;
                    const float p  = sigv[mt][r2] * __expf(acq[mt][r2] * 0.125f);
                    const ushort_t hi = f2bf(p);
                    const ushort_t lo = f2bf(p - bf2f(hi));
                    ps[lrow * 152 + tcol]      = hi;
                    ps[lrow * 152 + 64 + tcol] = lo;
                }
        }
        asm volatile("s_waitcnt lgkmcnt(0)" ::: "memory");
        __builtin_amdgcn_sched_barrier(0);
        __builtin_amdgcn_s_barrier();

        // ---- fused store (b128 ps reads) + row-sum partials ----
        {
            const int row = tid >> 2, c4 = tid & 3;
            const bf16x8 h0 = *(const bf16x8*)&ps[row * 152 + c4 * 16];
            const bf16x8 h1 = *(const bf16x8*)&ps[row * 152 + c4 * 16 + 8];
            const bf16x8 g0 = *(const bf16x8*)&ps[row * 152 + 64 + c4 * 16];
            const bf16x8 g1 = *(const bf16x8*)&ps[row * 152 + 64 + c4 * 16 + 8];
            float vbuf[16];
            float s = 0.f;
#pragma unroll
            for (int jj = 0; jj < 8; jj++) {
                vbuf[jj]     = bf2f((ushort_t)h0[jj]) + bf2f((ushort_t)g0[jj]);
                vbuf[8 + jj] = bf2f((ushort_t)h1[jj]) + bf2f((ushort_t)g1[jj]);
                s += vbuf[jj] + vbuf[8 + jj];
            }
            pacc += s;
            float* dstf = fused + ((size_t)hb * 512 + l0 + row) * 512 + t0 + c4 * 16;
#pragma unroll
            for (int jj = 0; jj < 4; jj++)
                *(float4*)(dstf + jj * 4) = *(float4*)&vbuf[jj * 4];
        }

        // ---- PV (V operands already in registers) ----
        {
#pragma unroll
            for (int mt = 0; mt < 4; mt++) {
                const int prow = mt * 16 + l15;
                const bf16x8 ph0 = *(const bf16x8*)&ps[prow * 152 + 0  + quad * 8];
                const bf16x8 ph1 = *(const bf16x8*)&ps[prow * 152 + 32 + quad * 8];
                const bf16x8 pl0 = *(const bf16x8*)&ps[prow * 152 + 64 + quad * 8];
                const bf16x8 pl1 = *(const bf16x8*)&ps[prow * 152 + 96 + quad * 8];
                f32x4 a = accpv[mt];
                a = __builtin_amdgcn_mfma_f32_16x16x32_bf16(ph0, bh0, a, 0, 0, 0);
                a = __builtin_amdgcn_mfma_f32_16x16x32_bf16(ph1, bh1, a, 0, 0, 0);
                a = __builtin_amdgcn_mfma_f32_16x16x32_bf16(ph0, bl0, a, 0, 0, 0);
                a = __builtin_amdgcn_mfma_f32_16x16x32_bf16(ph1, bl1, a, 0, 0, 0);
                a = __builtin_amdgcn_mfma_f32_16x16x32_bf16(pl0, bh0, a, 0, 0, 0);
                a = __builtin_amdgcn_mfma_f32_16x16x32_bf16(pl1, bh1, a, 0, 0, 0);
                accpv[mt] = a;
            }
        }
    }
    asm volatile("s_waitcnt vmcnt(0)" ::: "memory");   // drain dummy K(8) + stores

    // Row-sum: 4 partials of row (tid>>2) live in lanes c4=0..3 of one quad.
    pacc += __shfl_xor(pacc, 1);
    pacc += __shfl_xor(pacc, 2);
    __syncthreads();
    if ((tid & 3) == 0) ssum[tid >> 2] = pacc;
    __syncthreads();
    if (tid < 64) sums[(size_t)hb * 512 + l0 + tid] = ssum[tid];

#pragma unroll
    for (int mt = 0; mt < 4; mt++)
#pragma unroll
        for (int r2 = 0; r2 < 4; r2++) {
            const int lrow = mt * 16 + quad * 4 + r2;
            const float val = accpv[mt][r2] / ssum[lrow];
            const ushort_t hi = f2bf(val);
            const ushort_t lo = f2bf(val - bf2f(hi));
            const size_t obase = ((size_t)(b * 512 + l0 + lrow)) * K2_ + h * 64 + wv * 16 + l15;
            outp2[obase]       = hi;
            outp2[obase + D_]  = lo;
        }
}

// Scale fused_attn in place by 1/rowsum (HBM-BW-optimal as measured).
__global__ __launch_bounds__(256) void norm_kernel(
    float* __restrict__ fused, const float* __restrict__ sums)
{
    const int gi = blockIdx.x * 256 + threadIdx.x;
    float4* f4 = (float4*)fused;
    float4 v = f4[gi];
    const float inv = 1.f / sums[gi >> 7];
    v.x *= inv; v.y *= inv; v.z *= inv; v.w *= inv;
    f4[gi] = v;
}

// ---------------------------------------------------------------------------
extern "C" void kernel_launch(void* const* d_in, const int* in_sizes, int n_in,
                              void* d_out, int out_size, void* d_ws, size_t ws_size,
                              hipStream_t stream) {
    const float* q    = (const float*)d_in[0];
    const float* k    = (const float*)d_in[1];
    const float* v    = (const float*)d_in[2];
    const float* ploc = (const float*)d_in[3];
    const int*   mask = (const int*)  d_in[4];
    const float* Wq   = (const float*)d_in[5];
    const float* bq   = (const float*)d_in[6];
    const float* Wk   = (const float*)d_in[7];
    const float* bk   = (const float*)d_in[8];
    const float* Wv   = (const float*)d_in[9];
    const float* bv   = (const float*)d_in[10];
    const float* Wl   = (const float*)d_in[11];
    const float* bl   = (const float*)d_in[12];
    const float* Wf   = (const float*)d_in[13];
    const float* bf   = (const float*)d_in[14];

    // Arena. sig16 overlays [q2..WlT2 + gap], dead after projections.
    char* base = (char*)d_ws;
    short*    q2    = (short*)(base + 0);            // 12,582,912 B
    short*    k2    = (short*)(base + 12582912);
    short*    v2    = (short*)(base + 25165824);
    short*    WqT2  = (short*)(base + 37748736);
    short*    WkT2  = (short*)(base + 41287680);
    short*    WvT2  = (short*)(base + 44826624);
    short*    WlT2  = (short*)(base + 48365568);
    _Float16* sig16 = (_Float16*)(base + 0);         // 50,331,648 B overlay
    short*    WfT2  = (short*)(base + 50331648);
    ushort_t* qs2a  = (ushort_t*)(base + 53870592);  // 12,582,912 B
    ushort_t* ks2a  = (ushort_t*)(base + 66453504);
    ushort_t* vt2   = (ushort_t*)(base + 79036416);
    float*    swv   = (float*)(base + 91619328);     //  1,179,648 B
    float*    sums  = (float*)(base + 92798976);     //    196,608 B
    short*    outp2 = (short*)(base + 92995584);     // 12,582,912 B -> 105,578,496 total

    float* out   = (float*)d_out;
    float* fused = out + (size_t)4096 * D_;

    asplit_kernel<<<dim3(3, 4096, 3), 256, 0, stream>>>(q, k, v, q2, k2, v2);
    wsplit_kernel<<<dim3(12, 12, 5), 256, 0, stream>>>(
        Wq, Wk, Wv, Wl, Wf, WqT2, WkT2, WvT2, WlT2, WfT2);

    mfma_gemm<<<dim3(6, 32, 4), 256, 0, stream>>>(
        q2, k2, v2, WqT2, WkT2, WvT2, WlT2, WfT2,
        bq, bk, bv, bl, bf, outp2, qs2a, ks2a, vt2, swv, out, 0);

    sig_kernel<<<dim3(512, 8), 256, 0, stream>>>(ploc, swv, mask, sig16);

    attn_kernel<<<dim3(8, 8, 12), 256, 0, stream>>>(
        qs2a, ks2a, vt2, sig16, fused, (ushort_t*)outp2, sums);

    norm_kernel<<<dim3(24576), 256, 0, stream>>>(fused, sums);

    mfma_gemm<<<dim3(6, 32, 1), 256, 0, stream>>>(
        q2, k2, v2, WqT2, WkT2, WvT2, WlT2, WfT2,
        bq, bk, bv, bl, bf, outp2, qs2a, ks2a, vt2, swv, out, 4);
}